// Round 1
// baseline (321.775 us; speedup 1.0000x reference)
//
#include <hip/hip_runtime.h>
#include <stdint.h>

#define A_N 9
#define H_N 50
#define W_N 76
#define HW_N (H_N * W_N)      // 3800
#define N_PROP (A_N * HW_N)   // 34200
#define B_N 4
#define PRE_NMS 4000
#define POST_NMS 300
#define NMS_TH 0.7f
#define SORT_N 4096
#define MASK_WORDS 64
#define CAND_MAX 5120
#define NBINS 4096

// ---------------------------------------------------------------------------
// Kernel A: decode + keys (a-major mapping -> all loads/stores coalesced).
// Key low word encodes REFERENCE index n_ref = hw*9 + a so descending key
// order == jax.lax.top_k order (stable lower-index-first tie-break).
// ---------------------------------------------------------------------------
__global__ void decode_kernel(const float* __restrict__ scores,
                              const float* __restrict__ deltas,
                              const float* __restrict__ im_info,
                              const float* __restrict__ anchors,
                              float4* __restrict__ boxes,
                              unsigned long long* __restrict__ keys,
                              unsigned* __restrict__ ghist) {
#pragma clang fp contract(off)
    int gid = blockIdx.x * blockDim.x + threadIdx.x;
    if (gid >= B_N * N_PROP) return;
    int b = gid / N_PROP;
    int r = gid - b * N_PROP;
    int a = r / HW_N;          // fixed across a wave
    int hw = r - a * HW_N;     // consecutive across lanes
    int hy = hw / W_N;
    int wx = hw - hy * W_N;

    float sx = (float)wx * 16.0f;
    float sy = (float)hy * 16.0f;
    float ax1 = anchors[a * 4 + 0] + sx;
    float ay1 = anchors[a * 4 + 1] + sy;
    float ax2 = anchors[a * 4 + 2] + sx;
    float ay2 = anchors[a * 4 + 3] + sy;
    float aw = ax2 - ax1 + 1.0f;
    float ah = ay2 - ay1 + 1.0f;
    float cx = ax1 + 0.5f * aw;
    float cy = ay1 + 0.5f * ah;

    const float* db = deltas + ((size_t)b * 36 + (size_t)a * 4) * HW_N + hw;
    float d0 = db[0];
    float d1 = db[HW_N];
    float d2 = db[2 * HW_N];
    float d3 = db[3 * HW_N];

    float pcx = d0 * aw + cx;
    float pcy = d1 * ah + cy;
    float pw  = expf(d2) * aw;
    float ph  = expf(d3) * ah;

    float x1 = pcx - 0.5f * pw;
    float y1 = pcy - 0.5f * ph;
    float x2 = pcx + 0.5f * pw;
    float y2 = pcy + 0.5f * ph;

    float xhi = im_info[b * 3 + 1] - 1.0f;
    float yhi = im_info[b * 3 + 0] - 1.0f;
    x1 = fminf(fmaxf(x1, 0.0f), xhi);
    y1 = fminf(fmaxf(y1, 0.0f), yhi);
    x2 = fminf(fmaxf(x2, 0.0f), xhi);
    y2 = fminf(fmaxf(y2, 0.0f), yhi);

    boxes[gid] = make_float4(x1, y1, x2, y2);  // a-major layout

    float s = scores[((size_t)b * A_N + a) * HW_N + hw];
    unsigned f = __float_as_uint(s);
    unsigned sk = f ^ ((f & 0x80000000u) ? 0xFFFFFFFFu : 0x80000000u);
    unsigned n_ref = (unsigned)(hw * A_N + a);
    unsigned long long key = ((unsigned long long)sk << 32) | (unsigned)(~n_ref);
    keys[gid] = key;
    atomicAdd(&ghist[b * NBINS + (unsigned)(key >> 52)], 1u);
}

// ---------------------------------------------------------------------------
// Kernel B: threshold bucket T via two wave-level suffix scans (no serial
// tid==0 loop). T = largest bin with suffix-count >= PRE_NMS.
// ---------------------------------------------------------------------------
__global__ __launch_bounds__(64) void findT_kernel(const unsigned* __restrict__ ghist,
                                                   int* __restrict__ Tout) {
    __shared__ unsigned h[NBINS];
    int b = blockIdx.x;
    int lane = threadIdx.x;  // 64
    for (int i = lane; i < NBINS; i += 64) h[i] = ghist[b * NBINS + i];
    __syncthreads();
    unsigned gsum = 0;
    for (int j = 0; j < 64; ++j) gsum += h[lane * 64 + j];
    unsigned s = gsum;
    for (int d = 1; d < 64; d <<= 1) {
        unsigned t = (unsigned)__shfl_down((int)s, d);
        if (lane + d < 64) s += t;
    }
    // s[lane] = suffix sum of coarse groups
    unsigned long long bal = __ballot(s >= PRE_NMS);
    int gstar = 63 - __builtin_clzll(bal);
    unsigned after = (gstar < 63) ? (unsigned)__builtin_amdgcn_readlane((int)s, gstar + 1) : 0u;
    unsigned R = PRE_NMS - after;
    unsigned s2 = h[gstar * 64 + lane];
    for (int d = 1; d < 64; d <<= 1) {
        unsigned t = (unsigned)__shfl_down((int)s2, d);
        if (lane + d < 64) s2 += t;
    }
    unsigned long long bal2 = __ballot(s2 >= R);
    int j = 63 - __builtin_clzll(bal2);
    if (lane == 0) Tout[b] = gstar * 64 + j;
}

// ---------------------------------------------------------------------------
// Kernel C: compact candidates; wave-aggregated atomic.
// ---------------------------------------------------------------------------
__global__ void compact_kernel(const unsigned long long* __restrict__ keys,
                               const int* __restrict__ T,
                               unsigned* __restrict__ cnt,
                               unsigned long long* __restrict__ cand) {
    int b = blockIdx.y;
    int n = blockIdx.x * 256 + threadIdx.x;
    bool pred = false;
    unsigned long long k = 0ull;
    if (n < N_PROP) {
        k = keys[(size_t)b * N_PROP + n];
        pred = ((int)(unsigned)(k >> 52) >= T[b]);
    }
    unsigned long long m = __ballot(pred);
    if (m) {
        int lane = threadIdx.x & 63;
        int lead = __ffsll((unsigned long long)m) - 1;
        unsigned base = 0;
        if (lane == lead) base = atomicAdd(&cnt[b], (unsigned)__popcll(m));
        base = __shfl((int)base, lead);
        if (pred) {
            unsigned pos = base + (unsigned)__popcll(m & ((1ull << lane) - 1ull));
            if (pos < CAND_MAX) cand[(size_t)b * CAND_MAX + pos] = k;
        }
    }
}

// ---------------------------------------------------------------------------
// Kernel D: exact rank by pairwise count, 4-way j-split per candidate
// (tid>>2 = candidate, tid&3 = quarter of j-space), shfl-reduce partials.
// ---------------------------------------------------------------------------
__global__ __launch_bounds__(256) void rank_scatter_kernel(
    const unsigned long long* __restrict__ cand,
    const unsigned* __restrict__ cnt,
    const float4* __restrict__ boxes,
    float4* __restrict__ sortedBoxes) {
    __shared__ unsigned long long sk[256];
    int b = blockIdx.y;
    int tid = threadIdx.x;
    int ci = blockIdx.x * 64 + (tid >> 2);
    int q = tid & 3;
    int mc = (int)min(cnt[b], (unsigned)CAND_MAX);
    unsigned long long my = (ci < mc) ? cand[(size_t)b * CAND_MAX + ci] : 0ull;
    int rank = 0;
    int nt = (mc + 255) >> 8;
    for (int t = 0; t < nt; ++t) {
        int j = t * 256 + tid;
        sk[tid] = (j < mc) ? cand[(size_t)b * CAND_MAX + j] : 0ull;
        __syncthreads();
#pragma unroll 16
        for (int c = 0; c < 64; ++c) {
            int cc = q * 64 + ((c + q * 17) & 63);  // stagger: avoid 4-way bank conflict
            rank += (sk[cc] > my) ? 1 : 0;
        }
        __syncthreads();
    }
    rank += __shfl_xor(rank, 1);
    rank += __shfl_xor(rank, 2);
    if (q == 0 && ci < mc && rank < PRE_NMS) {
        unsigned n_ref = ~(unsigned)(my & 0xFFFFFFFFull);
        unsigned a = n_ref % A_N;
        unsigned hw = n_ref / A_N;
        sortedBoxes[(size_t)b * SORT_N + rank] =
            boxes[(size_t)b * N_PROP + a * HW_N + hw];
    }
    if (q == 1) {
        int pi = blockIdx.x * 64 + (tid >> 2);
        if (pi >= PRE_NMS && pi < SORT_N)
            sortedBoxes[(size_t)b * SORT_N + pi] = make_float4(0.f, 0.f, 0.f, 0.f);
    }
}

// ---------------------------------------------------------------------------
// Kernel E: suppression bitmask -> TWO layouts:
//   colmaj[cc*SORT_N + r]  (coalesced store; scan's diag/col prefetch reads)
//   rowmaj[r*64 + cc]      (scatter store; scan's kept-row loads COALESCED)
// Upper triangle only; lower-tri words stay poisoned in both copies but are
// provably consumed only after their read point has passed.
// ---------------------------------------------------------------------------
__global__ void iou_mask_kernel(const float4* __restrict__ sortedBoxes,
                                unsigned long long* __restrict__ colmaj,
                                unsigned long long* __restrict__ rowmaj) {
#pragma clang fp contract(off)
    int rc = blockIdx.x, cc = blockIdx.y, b = blockIdx.z;
    if (cc < rc) return;
    int t = threadIdx.x;
    __shared__ float4 colb[64];
    colb[t] = sortedBoxes[(size_t)b * SORT_N + cc * 64 + t];
    __syncthreads();
    int r = rc * 64 + t;
    float4 rb = sortedBoxes[(size_t)b * SORT_N + r];
    float rarea = (rb.z - rb.x) * (rb.w - rb.y);
    unsigned long long word = 0ull;
    for (int c = 0; c < 64; ++c) {
        int j = cc * 64 + c;
        float4 cb = colb[c];
        float carea = (cb.z - cb.x) * (cb.w - cb.y);
        float ltx = fmaxf(rb.x, cb.x);
        float lty = fmaxf(rb.y, cb.y);
        float rbx = fminf(rb.z, cb.z);
        float rby = fminf(rb.w, cb.w);
        float iw = fmaxf(rbx - ltx, 0.0f);
        float ih = fmaxf(rby - lty, 0.0f);
        float inter = iw * ih;
        float iou = inter / (rarea + carea - inter + 1e-9f);
        if (iou > NMS_TH && j > r) word |= (1ull << c);
    }
    colmaj[((size_t)b * MASK_WORDS + cc) * SORT_N + r] = word;   // coalesced
    rowmaj[((size_t)b * SORT_N + r) * MASK_WORDS + cc] = word;   // scatter (8B x 64 lines)
}

// ---------------------------------------------------------------------------
// Kernel F: group-tile greedy scan, latency-hidden.
//  - __launch_bounds__(64, 1): lift the VGPR cap so the 3 deferred-OR
//    generations (48 x u64 = 96 VGPRs) live in REGISTERS, not scratch
//  - kept-row loads come from the row-major mirror -> one contiguous 512 B
//    coalesced load per kept row (was: 64-line gather per load)
//  - diag/col prefetches stay on the col-major copy (coalesced)
//  - full kept-row loads are parked in 3 register generations and OR'd into
//    `rem` only 3 groups later -> vmcnt wait has ~2.5 group-times of slack
// ---------------------------------------------------------------------------
__device__ inline unsigned long long rl64(unsigned long long v, int src) {
    unsigned lo = (unsigned)__builtin_amdgcn_readlane((int)(unsigned)(v & 0xFFFFFFFFull), src);
    unsigned hi = (unsigned)__builtin_amdgcn_readlane((int)(unsigned)(v >> 32), src);
    return ((unsigned long long)hi << 32) | lo;
}

__global__ __launch_bounds__(64, 1) void nms_scan_kernel(
    const unsigned long long* __restrict__ colmaj,
    const unsigned long long* __restrict__ rowmaj,
    const float4* __restrict__ sortedBoxes,
    float* __restrict__ out) {
    int b = blockIdx.x;
    int lane = threadIdx.x;  // 0..63
    const unsigned long long* C = colmaj + (size_t)b * MASK_WORDS * SORT_N;
    const unsigned long long* R = rowmaj + (size_t)b * SORT_N * MASK_WORDS;
    __shared__ int kept[POST_NMS];

    unsigned long long rem = 0ull;          // lane w: removed bits of group w
    unsigned long long gA[16], gB[16], gC[16];
#pragma unroll
    for (int k = 0; k < 16; ++k) { gA[k] = 0; gB[k] = 0; gC[k] = 0; }

    // prefetch group 0: diag + words 1..3 over rows 0..63
    unsigned long long diag = C[lane];
    unsigned long long col1 = C[(size_t)1 * SORT_N + lane];
    unsigned long long col2 = C[(size_t)2 * SORT_N + lane];
    unsigned long long col3 = C[(size_t)3 * SORT_N + lane];

    unsigned long long d1c = 0, e2c = 0, e3c = 0;
    unsigned long long u2a = 0, u3a = 0, u3b = 0;
    int kcnt = 0;
    bool done = false;

    for (int g = 0; g < 64; ++g) {
        unsigned long long Dg = diag, c1 = col1, c2 = col2, c3 = col3;
        // issue prefetches for group g+1
        if (g < 63) {
            size_t rbase = (size_t)(g + 1) << 6;
            diag = C[(size_t)(g + 1) * SORT_N + rbase + lane];
            col1 = (g + 2 < 64) ? C[(size_t)(g + 2) * SORT_N + rbase + lane] : 0ull;
            col2 = (g + 3 < 64) ? C[(size_t)(g + 3) * SORT_N + rbase + lane] : 0ull;
            col3 = (g + 4 < 64) ? C[(size_t)(g + 4) * SORT_N + rbase + lane] : 0ull;
        }
        // retire generation A (rows from group g-3)
        unsigned long long accA = ((gA[0] | gA[1]) | (gA[2] | gA[3])) |
                                  ((gA[4] | gA[5]) | (gA[6] | gA[7])) |
                                  ((gA[8] | gA[9]) | (gA[10] | gA[11])) |
                                  ((gA[12] | gA[13]) | (gA[14] | gA[15]));
        rem |= accA;
#pragma unroll
        for (int k = 0; k < 16; ++k) { gA[k] = gB[k]; gB[k] = gC[k]; gC[k] = 0; }

        unsigned long long cur = rl64(rem, g) | d1c | e2c | e3c;
        unsigned long long pending = ~cur;
        unsigned long long alive = 0ull;
        while (pending) {
            int bit = __builtin_ctzll(pending);
            if (lane == 0) kept[kcnt] = (g << 6) + bit;
            ++kcnt;
            alive |= 1ull << bit;
            if (kcnt == POST_NMS) { done = true; break; }
            unsigned long long d = rl64(Dg, bit);
            pending &= ~(d | (1ull << bit));
        }
        if (done) break;

        // fast-path contributions of g's kept boxes to words g+1..g+3
        unsigned long long s1 = 0, s2 = 0, s3 = 0;
        unsigned long long am = alive;
        while (am) {
            int i = __builtin_ctzll(am); am &= am - 1;
            s1 |= rl64(c1, i);
            s2 |= rl64(c2, i);
            s3 |= rl64(c3, i);
        }
        e3c = u3b; u3b = u3a; u3a = s3;
        e2c = u2a; u2a = s2;
        d1c = s1;

        // full row loads for kept rows (deferred OR, 16-wide batch).
        // row-major mirror: lane = word index -> contiguous 512 B per row.
        unsigned long long am2 = alive;
        if (am2) {
            int idx[16];
            int i0 = __builtin_ctzll(am2); am2 &= am2 - 1;
            idx[0] = i0;
#pragma unroll
            for (int k = 1; k < 16; ++k) {
                idx[k] = am2 ? __builtin_ctzll(am2) : i0;
                am2 = am2 ? (am2 & (am2 - 1)) : 0ull;
            }
            size_t base = ((size_t)g << 6) * MASK_WORDS + lane;
#pragma unroll
            for (int k = 0; k < 16; ++k)
                gC[k] = R[base + (size_t)idx[k] * MASK_WORDS];
            while (am2) {  // >16 kept in one group: rare, accept the stall
                int j = __builtin_ctzll(am2); am2 &= am2 - 1;
                gC[0] |= R[base + (size_t)j * MASK_WORDS];
            }
        }
    }
    __syncthreads();
    for (int r = lane; r < POST_NMS; r += 64) {
        float* o = out + ((size_t)b * POST_NMS + r) * 5;
        float4 bx = make_float4(0.f, 0.f, 0.f, 0.f);
        if (r < kcnt) bx = sortedBoxes[(size_t)b * SORT_N + kept[r]];
        o[0] = (float)b;
        o[1] = bx.x;
        o[2] = bx.y;
        o[3] = bx.z;
        o[4] = bx.w;
    }
}

// ---------------------------------------------------------------------------
extern "C" void kernel_launch(void* const* d_in, const int* in_sizes, int n_in,
                              void* d_out, int out_size, void* d_ws, size_t ws_size,
                              hipStream_t stream) {
    const float* scores  = (const float*)d_in[0];
    const float* deltas  = (const float*)d_in[1];
    const float* im_info = (const float*)d_in[2];
    const float* anchors = (const float*)d_in[3];
    float* out = (float*)d_out;

    char* ws = (char*)d_ws;
    size_t off = 0;
    float4* boxes = (float4*)(ws + off);
    off += (size_t)B_N * N_PROP * sizeof(float4);
    off = (off + 255) & ~(size_t)255;
    unsigned long long* keys = (unsigned long long*)(ws + off);
    off += (size_t)B_N * N_PROP * sizeof(unsigned long long);
    off = (off + 255) & ~(size_t)255;
    float4* sortedBoxes = (float4*)(ws + off);
    off += (size_t)B_N * SORT_N * sizeof(float4);
    off = (off + 255) & ~(size_t)255;
    unsigned long long* colmaj = (unsigned long long*)(ws + off);
    off += (size_t)B_N * MASK_WORDS * SORT_N * sizeof(unsigned long long);
    off = (off + 255) & ~(size_t)255;
    unsigned long long* rowmaj = (unsigned long long*)(ws + off);
    off += (size_t)B_N * SORT_N * MASK_WORDS * sizeof(unsigned long long);
    off = (off + 255) & ~(size_t)255;
    unsigned long long* cand = (unsigned long long*)(ws + off);
    off += (size_t)B_N * CAND_MAX * sizeof(unsigned long long);
    off = (off + 255) & ~(size_t)255;
    unsigned* ghist = (unsigned*)(ws + off);
    size_t zero_off = off;
    off += (size_t)B_N * NBINS * sizeof(unsigned);
    unsigned* cnt = (unsigned*)(ws + off);
    off += (size_t)B_N * sizeof(unsigned);
    size_t zero_bytes = off - zero_off;
    off = (off + 255) & ~(size_t)255;
    int* Tbuf = (int*)(ws + off);
    off += (size_t)B_N * sizeof(int);

    hipMemsetAsync((void*)ghist, 0, zero_bytes, stream);

    int total = B_N * N_PROP;
    decode_kernel<<<(total + 255) / 256, 256, 0, stream>>>(
        scores, deltas, im_info, anchors, boxes, keys, ghist);
    findT_kernel<<<B_N, 64, 0, stream>>>(ghist, Tbuf);
    compact_kernel<<<dim3((N_PROP + 255) / 256, B_N), 256, 0, stream>>>(
        keys, Tbuf, cnt, cand);
    rank_scatter_kernel<<<dim3(CAND_MAX / 64, B_N), 256, 0, stream>>>(
        cand, cnt, boxes, sortedBoxes);
    iou_mask_kernel<<<dim3(64, 64, B_N), 64, 0, stream>>>(sortedBoxes, colmaj, rowmaj);
    nms_scan_kernel<<<B_N, 64, 0, stream>>>(colmaj, rowmaj, sortedBoxes, out);
}

// Round 2
// 318.122 us; speedup vs baseline: 1.0115x; 1.0115x over previous
//
#include <hip/hip_runtime.h>
#include <stdint.h>

#define A_N 9
#define H_N 50
#define W_N 76
#define HW_N (H_N * W_N)      // 3800
#define N_PROP (A_N * HW_N)   // 34200
#define B_N 4
#define PRE_NMS 4000
#define POST_NMS 300
#define NMS_TH 0.7f
#define SORT_N 4096
#define MASK_WORDS 64
#define CAND_MAX 5120
#define NBINS 4096

// ---------------------------------------------------------------------------
// Kernel A: decode + keys (a-major mapping -> all loads/stores coalesced).
// Key low word encodes REFERENCE index n_ref = hw*9 + a so descending key
// order == jax.lax.top_k order (stable lower-index-first tie-break).
// ---------------------------------------------------------------------------
__global__ void decode_kernel(const float* __restrict__ scores,
                              const float* __restrict__ deltas,
                              const float* __restrict__ im_info,
                              const float* __restrict__ anchors,
                              float4* __restrict__ boxes,
                              unsigned long long* __restrict__ keys,
                              unsigned* __restrict__ ghist) {
#pragma clang fp contract(off)
    int gid = blockIdx.x * blockDim.x + threadIdx.x;
    if (gid >= B_N * N_PROP) return;
    int b = gid / N_PROP;
    int r = gid - b * N_PROP;
    int a = r / HW_N;          // fixed across a wave
    int hw = r - a * HW_N;     // consecutive across lanes
    int hy = hw / W_N;
    int wx = hw - hy * W_N;

    float sx = (float)wx * 16.0f;
    float sy = (float)hy * 16.0f;
    float ax1 = anchors[a * 4 + 0] + sx;
    float ay1 = anchors[a * 4 + 1] + sy;
    float ax2 = anchors[a * 4 + 2] + sx;
    float ay2 = anchors[a * 4 + 3] + sy;
    float aw = ax2 - ax1 + 1.0f;
    float ah = ay2 - ay1 + 1.0f;
    float cx = ax1 + 0.5f * aw;
    float cy = ay1 + 0.5f * ah;

    const float* db = deltas + ((size_t)b * 36 + (size_t)a * 4) * HW_N + hw;
    float d0 = db[0];
    float d1 = db[HW_N];
    float d2 = db[2 * HW_N];
    float d3 = db[3 * HW_N];

    float pcx = d0 * aw + cx;
    float pcy = d1 * ah + cy;
    float pw  = expf(d2) * aw;
    float ph  = expf(d3) * ah;

    float x1 = pcx - 0.5f * pw;
    float y1 = pcy - 0.5f * ph;
    float x2 = pcx + 0.5f * pw;
    float y2 = pcy + 0.5f * ph;

    float xhi = im_info[b * 3 + 1] - 1.0f;
    float yhi = im_info[b * 3 + 0] - 1.0f;
    x1 = fminf(fmaxf(x1, 0.0f), xhi);
    y1 = fminf(fmaxf(y1, 0.0f), yhi);
    x2 = fminf(fmaxf(x2, 0.0f), xhi);
    y2 = fminf(fmaxf(y2, 0.0f), yhi);

    boxes[gid] = make_float4(x1, y1, x2, y2);  // a-major layout

    float s = scores[((size_t)b * A_N + a) * HW_N + hw];
    unsigned f = __float_as_uint(s);
    unsigned sk = f ^ ((f & 0x80000000u) ? 0xFFFFFFFFu : 0x80000000u);
    unsigned n_ref = (unsigned)(hw * A_N + a);
    unsigned long long key = ((unsigned long long)sk << 32) | (unsigned)(~n_ref);
    keys[gid] = key;
    atomicAdd(&ghist[b * NBINS + (unsigned)(key >> 52)], 1u);
}

// ---------------------------------------------------------------------------
// Kernel B: threshold bucket T via two wave-level suffix scans.
// ---------------------------------------------------------------------------
__global__ __launch_bounds__(64) void findT_kernel(const unsigned* __restrict__ ghist,
                                                   int* __restrict__ Tout) {
    __shared__ unsigned h[NBINS];
    int b = blockIdx.x;
    int lane = threadIdx.x;  // 64
    for (int i = lane; i < NBINS; i += 64) h[i] = ghist[b * NBINS + i];
    __syncthreads();
    unsigned gsum = 0;
    for (int j = 0; j < 64; ++j) gsum += h[lane * 64 + j];
    unsigned s = gsum;
    for (int d = 1; d < 64; d <<= 1) {
        unsigned t = (unsigned)__shfl_down((int)s, d);
        if (lane + d < 64) s += t;
    }
    unsigned long long bal = __ballot(s >= PRE_NMS);
    int gstar = 63 - __builtin_clzll(bal);
    unsigned after = (gstar < 63) ? (unsigned)__builtin_amdgcn_readlane((int)s, gstar + 1) : 0u;
    unsigned R = PRE_NMS - after;
    unsigned s2 = h[gstar * 64 + lane];
    for (int d = 1; d < 64; d <<= 1) {
        unsigned t = (unsigned)__shfl_down((int)s2, d);
        if (lane + d < 64) s2 += t;
    }
    unsigned long long bal2 = __ballot(s2 >= R);
    int j = 63 - __builtin_clzll(bal2);
    if (lane == 0) Tout[b] = gstar * 64 + j;
}

// ---------------------------------------------------------------------------
// Kernel C: compact candidates; wave-aggregated atomic.
// ---------------------------------------------------------------------------
__global__ void compact_kernel(const unsigned long long* __restrict__ keys,
                               const int* __restrict__ T,
                               unsigned* __restrict__ cnt,
                               unsigned long long* __restrict__ cand) {
    int b = blockIdx.y;
    int n = blockIdx.x * 256 + threadIdx.x;
    bool pred = false;
    unsigned long long k = 0ull;
    if (n < N_PROP) {
        k = keys[(size_t)b * N_PROP + n];
        pred = ((int)(unsigned)(k >> 52) >= T[b]);
    }
    unsigned long long m = __ballot(pred);
    if (m) {
        int lane = threadIdx.x & 63;
        int lead = __ffsll((unsigned long long)m) - 1;
        unsigned base = 0;
        if (lane == lead) base = atomicAdd(&cnt[b], (unsigned)__popcll(m));
        base = __shfl((int)base, lead);
        if (pred) {
            unsigned pos = base + (unsigned)__popcll(m & ((1ull << lane) - 1ull));
            if (pos < CAND_MAX) cand[(size_t)b * CAND_MAX + pos] = k;
        }
    }
}

// ---------------------------------------------------------------------------
// Kernel D: exact rank by pairwise count, 4-way j-split per candidate.
// ---------------------------------------------------------------------------
__global__ __launch_bounds__(256) void rank_scatter_kernel(
    const unsigned long long* __restrict__ cand,
    const unsigned* __restrict__ cnt,
    const float4* __restrict__ boxes,
    float4* __restrict__ sortedBoxes) {
    __shared__ unsigned long long sk[256];
    int b = blockIdx.y;
    int tid = threadIdx.x;
    int ci = blockIdx.x * 64 + (tid >> 2);
    int q = tid & 3;
    int mc = (int)min(cnt[b], (unsigned)CAND_MAX);
    unsigned long long my = (ci < mc) ? cand[(size_t)b * CAND_MAX + ci] : 0ull;
    int rank = 0;
    int nt = (mc + 255) >> 8;
    for (int t = 0; t < nt; ++t) {
        int j = t * 256 + tid;
        sk[tid] = (j < mc) ? cand[(size_t)b * CAND_MAX + j] : 0ull;
        __syncthreads();
#pragma unroll 16
        for (int c = 0; c < 64; ++c) {
            int cc = q * 64 + ((c + q * 17) & 63);  // stagger: avoid 4-way bank conflict
            rank += (sk[cc] > my) ? 1 : 0;
        }
        __syncthreads();
    }
    rank += __shfl_xor(rank, 1);
    rank += __shfl_xor(rank, 2);
    if (q == 0 && ci < mc && rank < PRE_NMS) {
        unsigned n_ref = ~(unsigned)(my & 0xFFFFFFFFull);
        unsigned a = n_ref % A_N;
        unsigned hw = n_ref / A_N;
        sortedBoxes[(size_t)b * SORT_N + rank] =
            boxes[(size_t)b * N_PROP + a * HW_N + hw];
    }
    if (q == 1) {
        int pi = blockIdx.x * 64 + (tid >> 2);
        if (pi >= PRE_NMS && pi < SORT_N)
            sortedBoxes[(size_t)b * SORT_N + pi] = make_float4(0.f, 0.f, 0.f, 0.f);
    }
}

// ---------------------------------------------------------------------------
// Kernel E: suppression bitmask -> TWO layouts:
//   colmaj[cc*SORT_N + r]  (coalesced store; scan's diag/col prefetch reads)
//   rowmaj[r*64 + cc]      (scatter store; scan's kept-row loads COALESCED)
// ---------------------------------------------------------------------------
__global__ void iou_mask_kernel(const float4* __restrict__ sortedBoxes,
                                unsigned long long* __restrict__ colmaj,
                                unsigned long long* __restrict__ rowmaj) {
#pragma clang fp contract(off)
    int rc = blockIdx.x, cc = blockIdx.y, b = blockIdx.z;
    if (cc < rc) return;
    int t = threadIdx.x;
    __shared__ float4 colb[64];
    colb[t] = sortedBoxes[(size_t)b * SORT_N + cc * 64 + t];
    __syncthreads();
    int r = rc * 64 + t;
    float4 rb = sortedBoxes[(size_t)b * SORT_N + r];
    float rarea = (rb.z - rb.x) * (rb.w - rb.y);
    unsigned long long word = 0ull;
    for (int c = 0; c < 64; ++c) {
        int j = cc * 64 + c;
        float4 cb = colb[c];
        float carea = (cb.z - cb.x) * (cb.w - cb.y);
        float ltx = fmaxf(rb.x, cb.x);
        float lty = fmaxf(rb.y, cb.y);
        float rbx = fminf(rb.z, cb.z);
        float rby = fminf(rb.w, cb.w);
        float iw = fmaxf(rbx - ltx, 0.0f);
        float ih = fmaxf(rby - lty, 0.0f);
        float inter = iw * ih;
        float iou = inter / (rarea + carea - inter + 1e-9f);
        if (iou > NMS_TH && j > r) word |= (1ull << c);
    }
    colmaj[((size_t)b * MASK_WORDS + cc) * SORT_N + r] = word;   // coalesced
    rowmaj[((size_t)b * SORT_N + r) * MASK_WORDS + cc] = word;   // scatter
}

// ---------------------------------------------------------------------------
// Kernel F: group-tile greedy scan, latency-hidden.
//  - 48 NAMED u64 variables (no arrays -> guaranteed VGPR residency; the
//    array version was demoted to scratch: VGPR_Count 76 proves 48 u64
//    could not have been register-resident)
//  - 3-stage MODULO SCHEDULE: group loop unrolled x3; generation X is
//    retired at step g and reloaded at step g, next read at g+3. No
//    cross-generation register moves -> the compiler's counted vmcnt defers
//    each generation's wait ~3 group-times (greedy scans of g+1, g+2).
//  - kept-row loads from row-major mirror: one contiguous 512 B coalesced
//    load per kept row. diag/col prefetches stay on col-major (coalesced).
// ---------------------------------------------------------------------------
__device__ inline unsigned long long rl64(unsigned long long v, int src) {
    unsigned lo = (unsigned)__builtin_amdgcn_readlane((int)(unsigned)(v & 0xFFFFFFFFull), src);
    unsigned hi = (unsigned)__builtin_amdgcn_readlane((int)(unsigned)(v >> 32), src);
    return ((unsigned long long)hi << 32) | lo;
}

#define OR16(X) (((((X##0 | X##1) | (X##2 | X##3)) | ((X##4 | X##5) | (X##6 | X##7))) | \
                  (((X##8 | X##9) | (X##10 | X##11)) | ((X##12 | X##13) | (X##14 | X##15)))))

#define ZERO16(X) do { X##0=0;X##1=0;X##2=0;X##3=0;X##4=0;X##5=0;X##6=0;X##7=0; \
                       X##8=0;X##9=0;X##10=0;X##11=0;X##12=0;X##13=0;X##14=0;X##15=0; } while (0)

#define EXTN(ik) int ik = am2 ? __builtin_ctzll(am2) : i0; am2 = am2 ? (am2 & (am2 - 1)) : 0ull;

#define NMS_STEP(X, G)                                                         \
    if (!done && (G) < 64) {                                                   \
        const int g_ = (G);                                                    \
        unsigned long long Dg = diag, c1 = col1, c2 = col2, c3 = col3;         \
        if (g_ < 63) {                                                         \
            size_t rbase = (size_t)(g_ + 1) << 6;                              \
            diag = C[(size_t)(g_ + 1) * SORT_N + rbase + lane];                \
            col1 = (g_ + 2 < 64) ? C[(size_t)(g_ + 2) * SORT_N + rbase + lane] : 0ull; \
            col2 = (g_ + 3 < 64) ? C[(size_t)(g_ + 3) * SORT_N + rbase + lane] : 0ull; \
            col3 = (g_ + 4 < 64) ? C[(size_t)(g_ + 4) * SORT_N + rbase + lane] : 0ull; \
        }                                                                      \
        rem |= OR16(X);   /* retire generation X: loads issued at step g-3 */  \
        ZERO16(X);                                                             \
        unsigned long long cur = rl64(rem, g_) | d1c | e2c | e3c;              \
        unsigned long long pending = ~cur;                                     \
        unsigned long long alive = 0ull;                                       \
        while (pending) {                                                      \
            int bit = __builtin_ctzll(pending);                                \
            if (lane == 0) kept[kcnt] = (g_ << 6) + bit;                       \
            ++kcnt;                                                            \
            alive |= 1ull << bit;                                              \
            if (kcnt == POST_NMS) { done = true; break; }                      \
            unsigned long long d = rl64(Dg, bit);                              \
            pending &= ~(d | (1ull << bit));                                   \
        }                                                                      \
        if (!done) {                                                           \
            unsigned long long s1 = 0, s2 = 0, s3 = 0;                         \
            unsigned long long am = alive;                                     \
            while (am) {                                                       \
                int i = __builtin_ctzll(am); am &= am - 1;                     \
                s1 |= rl64(c1, i); s2 |= rl64(c2, i); s3 |= rl64(c3, i);       \
            }                                                                  \
            e3c = u3b; u3b = u3a; u3a = s3;                                    \
            e2c = u2a; u2a = s2;                                               \
            d1c = s1;                                                          \
            if (alive) {                                                       \
                unsigned long long am2 = alive;                                \
                int i0 = __builtin_ctzll(am2); am2 &= am2 - 1;                 \
                EXTN(i1)  EXTN(i2)  EXTN(i3)  EXTN(i4)  EXTN(i5)               \
                EXTN(i6)  EXTN(i7)  EXTN(i8)  EXTN(i9)  EXTN(i10)              \
                EXTN(i11) EXTN(i12) EXTN(i13) EXTN(i14) EXTN(i15)              \
                size_t base = ((size_t)g_ << 6) * MASK_WORDS + lane;           \
                X##0  = R[base + (size_t)i0  * MASK_WORDS];                    \
                X##1  = R[base + (size_t)i1  * MASK_WORDS];                    \
                X##2  = R[base + (size_t)i2  * MASK_WORDS];                    \
                X##3  = R[base + (size_t)i3  * MASK_WORDS];                    \
                X##4  = R[base + (size_t)i4  * MASK_WORDS];                    \
                X##5  = R[base + (size_t)i5  * MASK_WORDS];                    \
                X##6  = R[base + (size_t)i6  * MASK_WORDS];                    \
                X##7  = R[base + (size_t)i7  * MASK_WORDS];                    \
                X##8  = R[base + (size_t)i8  * MASK_WORDS];                    \
                X##9  = R[base + (size_t)i9  * MASK_WORDS];                    \
                X##10 = R[base + (size_t)i10 * MASK_WORDS];                    \
                X##11 = R[base + (size_t)i11 * MASK_WORDS];                    \
                X##12 = R[base + (size_t)i12 * MASK_WORDS];                    \
                X##13 = R[base + (size_t)i13 * MASK_WORDS];                    \
                X##14 = R[base + (size_t)i14 * MASK_WORDS];                    \
                X##15 = R[base + (size_t)i15 * MASK_WORDS];                    \
                while (am2) { /* >16 kept in one group: rare, accept stall */  \
                    int j = __builtin_ctzll(am2); am2 &= am2 - 1;              \
                    X##0 |= R[base + (size_t)j * MASK_WORDS];                  \
                }                                                              \
            }                                                                  \
        }                                                                      \
    }

__global__ __launch_bounds__(64, 1) void nms_scan_kernel(
    const unsigned long long* __restrict__ colmaj,
    const unsigned long long* __restrict__ rowmaj,
    const float4* __restrict__ sortedBoxes,
    float* __restrict__ out) {
    int b = blockIdx.x;
    int lane = threadIdx.x;  // 0..63
    const unsigned long long* C = colmaj + (size_t)b * MASK_WORDS * SORT_N;
    const unsigned long long* R = rowmaj + (size_t)b * SORT_N * MASK_WORDS;
    __shared__ int kept[POST_NMS];

    unsigned long long rem = 0ull;  // lane w: removed bits of group w
    // three generations of 16 named u64 (forced register residency)
    unsigned long long qa0=0,qa1=0,qa2=0,qa3=0,qa4=0,qa5=0,qa6=0,qa7=0,
                       qa8=0,qa9=0,qa10=0,qa11=0,qa12=0,qa13=0,qa14=0,qa15=0;
    unsigned long long qb0=0,qb1=0,qb2=0,qb3=0,qb4=0,qb5=0,qb6=0,qb7=0,
                       qb8=0,qb9=0,qb10=0,qb11=0,qb12=0,qb13=0,qb14=0,qb15=0;
    unsigned long long qc0=0,qc1=0,qc2=0,qc3=0,qc4=0,qc5=0,qc6=0,qc7=0,
                       qc8=0,qc9=0,qc10=0,qc11=0,qc12=0,qc13=0,qc14=0,qc15=0;

    // prefetch group 0: diag + words 1..3 over rows 0..63
    unsigned long long diag = C[lane];
    unsigned long long col1 = C[(size_t)1 * SORT_N + lane];
    unsigned long long col2 = C[(size_t)2 * SORT_N + lane];
    unsigned long long col3 = C[(size_t)3 * SORT_N + lane];

    unsigned long long d1c = 0, e2c = 0, e3c = 0;
    unsigned long long u2a = 0, u3a = 0, u3b = 0;
    int kcnt = 0;
    bool done = false;

    for (int gg = 0; gg < 64; gg += 3) {
        NMS_STEP(qa, gg)
        NMS_STEP(qb, gg + 1)
        NMS_STEP(qc, gg + 2)
        if (done) break;
    }

    __syncthreads();
    for (int r = lane; r < POST_NMS; r += 64) {
        float* o = out + ((size_t)b * POST_NMS + r) * 5;
        float4 bx = make_float4(0.f, 0.f, 0.f, 0.f);
        if (r < kcnt) bx = sortedBoxes[(size_t)b * SORT_N + kept[r]];
        o[0] = (float)b;
        o[1] = bx.x;
        o[2] = bx.y;
        o[3] = bx.z;
        o[4] = bx.w;
    }
}

// ---------------------------------------------------------------------------
extern "C" void kernel_launch(void* const* d_in, const int* in_sizes, int n_in,
                              void* d_out, int out_size, void* d_ws, size_t ws_size,
                              hipStream_t stream) {
    const float* scores  = (const float*)d_in[0];
    const float* deltas  = (const float*)d_in[1];
    const float* im_info = (const float*)d_in[2];
    const float* anchors = (const float*)d_in[3];
    float* out = (float*)d_out;

    char* ws = (char*)d_ws;
    size_t off = 0;
    float4* boxes = (float4*)(ws + off);
    off += (size_t)B_N * N_PROP * sizeof(float4);
    off = (off + 255) & ~(size_t)255;
    unsigned long long* keys = (unsigned long long*)(ws + off);
    off += (size_t)B_N * N_PROP * sizeof(unsigned long long);
    off = (off + 255) & ~(size_t)255;
    float4* sortedBoxes = (float4*)(ws + off);
    off += (size_t)B_N * SORT_N * sizeof(float4);
    off = (off + 255) & ~(size_t)255;
    unsigned long long* colmaj = (unsigned long long*)(ws + off);
    off += (size_t)B_N * MASK_WORDS * SORT_N * sizeof(unsigned long long);
    off = (off + 255) & ~(size_t)255;
    unsigned long long* rowmaj = (unsigned long long*)(ws + off);
    off += (size_t)B_N * SORT_N * MASK_WORDS * sizeof(unsigned long long);
    off = (off + 255) & ~(size_t)255;
    unsigned long long* cand = (unsigned long long*)(ws + off);
    off += (size_t)B_N * CAND_MAX * sizeof(unsigned long long);
    off = (off + 255) & ~(size_t)255;
    unsigned* ghist = (unsigned*)(ws + off);
    size_t zero_off = off;
    off += (size_t)B_N * NBINS * sizeof(unsigned);
    unsigned* cnt = (unsigned*)(ws + off);
    off += (size_t)B_N * sizeof(unsigned);
    size_t zero_bytes = off - zero_off;
    off = (off + 255) & ~(size_t)255;
    int* Tbuf = (int*)(ws + off);
    off += (size_t)B_N * sizeof(int);

    hipMemsetAsync((void*)ghist, 0, zero_bytes, stream);

    int total = B_N * N_PROP;
    decode_kernel<<<(total + 255) / 256, 256, 0, stream>>>(
        scores, deltas, im_info, anchors, boxes, keys, ghist);
    findT_kernel<<<B_N, 64, 0, stream>>>(ghist, Tbuf);
    compact_kernel<<<dim3((N_PROP + 255) / 256, B_N), 256, 0, stream>>>(
        keys, Tbuf, cnt, cand);
    rank_scatter_kernel<<<dim3(CAND_MAX / 64, B_N), 256, 0, stream>>>(
        cand, cnt, boxes, sortedBoxes);
    iou_mask_kernel<<<dim3(64, 64, B_N), 64, 0, stream>>>(sortedBoxes, colmaj, rowmaj);
    nms_scan_kernel<<<B_N, 64, 0, stream>>>(colmaj, rowmaj, sortedBoxes, out);
}

// Round 3
// 312.769 us; speedup vs baseline: 1.0288x; 1.0171x over previous
//
#include <hip/hip_runtime.h>
#include <stdint.h>

#define A_N 9
#define H_N 50
#define W_N 76
#define HW_N (H_N * W_N)      // 3800
#define N_PROP (A_N * HW_N)   // 34200
#define B_N 4
#define PRE_NMS 4000
#define POST_NMS 300
#define NMS_TH 0.7f
#define SORT_N 4096
#define MASK_WORDS 64
#define CAND_MAX 5120
#define NBINS 4096

// ---------------------------------------------------------------------------
// Kernel A: decode + keys (a-major mapping -> all loads/stores coalesced).
// ---------------------------------------------------------------------------
__global__ void decode_kernel(const float* __restrict__ scores,
                              const float* __restrict__ deltas,
                              const float* __restrict__ im_info,
                              const float* __restrict__ anchors,
                              float4* __restrict__ boxes,
                              unsigned long long* __restrict__ keys,
                              unsigned* __restrict__ ghist) {
#pragma clang fp contract(off)
    int gid = blockIdx.x * blockDim.x + threadIdx.x;
    if (gid >= B_N * N_PROP) return;
    int b = gid / N_PROP;
    int r = gid - b * N_PROP;
    int a = r / HW_N;          // fixed across a wave
    int hw = r - a * HW_N;     // consecutive across lanes
    int hy = hw / W_N;
    int wx = hw - hy * W_N;

    float sx = (float)wx * 16.0f;
    float sy = (float)hy * 16.0f;
    float ax1 = anchors[a * 4 + 0] + sx;
    float ay1 = anchors[a * 4 + 1] + sy;
    float ax2 = anchors[a * 4 + 2] + sx;
    float ay2 = anchors[a * 4 + 3] + sy;
    float aw = ax2 - ax1 + 1.0f;
    float ah = ay2 - ay1 + 1.0f;
    float cx = ax1 + 0.5f * aw;
    float cy = ay1 + 0.5f * ah;

    const float* db = deltas + ((size_t)b * 36 + (size_t)a * 4) * HW_N + hw;
    float d0 = db[0];
    float d1 = db[HW_N];
    float d2 = db[2 * HW_N];
    float d3 = db[3 * HW_N];

    float pcx = d0 * aw + cx;
    float pcy = d1 * ah + cy;
    float pw  = expf(d2) * aw;
    float ph  = expf(d3) * ah;

    float x1 = pcx - 0.5f * pw;
    float y1 = pcy - 0.5f * ph;
    float x2 = pcx + 0.5f * pw;
    float y2 = pcy + 0.5f * ph;

    float xhi = im_info[b * 3 + 1] - 1.0f;
    float yhi = im_info[b * 3 + 0] - 1.0f;
    x1 = fminf(fmaxf(x1, 0.0f), xhi);
    y1 = fminf(fmaxf(y1, 0.0f), yhi);
    x2 = fminf(fmaxf(x2, 0.0f), xhi);
    y2 = fminf(fmaxf(y2, 0.0f), yhi);

    boxes[gid] = make_float4(x1, y1, x2, y2);  // a-major layout

    float s = scores[((size_t)b * A_N + a) * HW_N + hw];
    unsigned f = __float_as_uint(s);
    unsigned sk = f ^ ((f & 0x80000000u) ? 0xFFFFFFFFu : 0x80000000u);
    unsigned n_ref = (unsigned)(hw * A_N + a);
    unsigned long long key = ((unsigned long long)sk << 32) | (unsigned)(~n_ref);
    keys[gid] = key;
    atomicAdd(&ghist[b * NBINS + (unsigned)(key >> 52)], 1u);
}

// ---------------------------------------------------------------------------
// Kernel B: threshold bucket T via two wave-level suffix scans.
// ---------------------------------------------------------------------------
__global__ __launch_bounds__(64) void findT_kernel(const unsigned* __restrict__ ghist,
                                                   int* __restrict__ Tout) {
    __shared__ unsigned h[NBINS];
    int b = blockIdx.x;
    int lane = threadIdx.x;  // 64
    for (int i = lane; i < NBINS; i += 64) h[i] = ghist[b * NBINS + i];
    __syncthreads();
    unsigned gsum = 0;
    for (int j = 0; j < 64; ++j) gsum += h[lane * 64 + j];
    unsigned s = gsum;
    for (int d = 1; d < 64; d <<= 1) {
        unsigned t = (unsigned)__shfl_down((int)s, d);
        if (lane + d < 64) s += t;
    }
    unsigned long long bal = __ballot(s >= PRE_NMS);
    int gstar = 63 - __builtin_clzll(bal);
    unsigned after = (gstar < 63) ? (unsigned)__builtin_amdgcn_readlane((int)s, gstar + 1) : 0u;
    unsigned R = PRE_NMS - after;
    unsigned s2 = h[gstar * 64 + lane];
    for (int d = 1; d < 64; d <<= 1) {
        unsigned t = (unsigned)__shfl_down((int)s2, d);
        if (lane + d < 64) s2 += t;
    }
    unsigned long long bal2 = __ballot(s2 >= R);
    int j = 63 - __builtin_clzll(bal2);
    if (lane == 0) Tout[b] = gstar * 64 + j;
}

// ---------------------------------------------------------------------------
// Kernel C: compact candidates; wave-aggregated atomic.
// ---------------------------------------------------------------------------
__global__ void compact_kernel(const unsigned long long* __restrict__ keys,
                               const int* __restrict__ T,
                               unsigned* __restrict__ cnt,
                               unsigned long long* __restrict__ cand) {
    int b = blockIdx.y;
    int n = blockIdx.x * 256 + threadIdx.x;
    bool pred = false;
    unsigned long long k = 0ull;
    if (n < N_PROP) {
        k = keys[(size_t)b * N_PROP + n];
        pred = ((int)(unsigned)(k >> 52) >= T[b]);
    }
    unsigned long long m = __ballot(pred);
    if (m) {
        int lane = threadIdx.x & 63;
        int lead = __ffsll((unsigned long long)m) - 1;
        unsigned base = 0;
        if (lane == lead) base = atomicAdd(&cnt[b], (unsigned)__popcll(m));
        base = __shfl((int)base, lead);
        if (pred) {
            unsigned pos = base + (unsigned)__popcll(m & ((1ull << lane) - 1ull));
            if (pos < CAND_MAX) cand[(size_t)b * CAND_MAX + pos] = k;
        }
    }
}

// ---------------------------------------------------------------------------
// Kernel D: exact rank by pairwise count, 4-way j-split per candidate.
// ---------------------------------------------------------------------------
__global__ __launch_bounds__(256) void rank_scatter_kernel(
    const unsigned long long* __restrict__ cand,
    const unsigned* __restrict__ cnt,
    const float4* __restrict__ boxes,
    float4* __restrict__ sortedBoxes) {
    __shared__ unsigned long long sk[256];
    int b = blockIdx.y;
    int tid = threadIdx.x;
    int ci = blockIdx.x * 64 + (tid >> 2);
    int q = tid & 3;
    int mc = (int)min(cnt[b], (unsigned)CAND_MAX);
    unsigned long long my = (ci < mc) ? cand[(size_t)b * CAND_MAX + ci] : 0ull;
    int rank = 0;
    int nt = (mc + 255) >> 8;
    for (int t = 0; t < nt; ++t) {
        int j = t * 256 + tid;
        sk[tid] = (j < mc) ? cand[(size_t)b * CAND_MAX + j] : 0ull;
        __syncthreads();
#pragma unroll 16
        for (int c = 0; c < 64; ++c) {
            int cc = q * 64 + ((c + q * 17) & 63);  // stagger: avoid 4-way bank conflict
            rank += (sk[cc] > my) ? 1 : 0;
        }
        __syncthreads();
    }
    rank += __shfl_xor(rank, 1);
    rank += __shfl_xor(rank, 2);
    if (q == 0 && ci < mc && rank < PRE_NMS) {
        unsigned n_ref = ~(unsigned)(my & 0xFFFFFFFFull);
        unsigned a = n_ref % A_N;
        unsigned hw = n_ref / A_N;
        sortedBoxes[(size_t)b * SORT_N + rank] =
            boxes[(size_t)b * N_PROP + a * HW_N + hw];
    }
    if (q == 1) {
        int pi = blockIdx.x * 64 + (tid >> 2);
        if (pi >= PRE_NMS && pi < SORT_N)
            sortedBoxes[(size_t)b * SORT_N + pi] = make_float4(0.f, 0.f, 0.f, 0.f);
    }
}

// ---------------------------------------------------------------------------
// Kernel E: suppression bitmask -> TWO layouts:
//   colmaj[cc*SORT_N + r]  (coalesced store; scan's diag/col prefetch reads)
//   rowmaj[r*64 + cc]      (scatter store; scan's kept-row loads COALESCED)
// ---------------------------------------------------------------------------
__global__ void iou_mask_kernel(const float4* __restrict__ sortedBoxes,
                                unsigned long long* __restrict__ colmaj,
                                unsigned long long* __restrict__ rowmaj) {
#pragma clang fp contract(off)
    int rc = blockIdx.x, cc = blockIdx.y, b = blockIdx.z;
    if (cc < rc) return;
    int t = threadIdx.x;
    __shared__ float4 colb[64];
    colb[t] = sortedBoxes[(size_t)b * SORT_N + cc * 64 + t];
    __syncthreads();
    int r = rc * 64 + t;
    float4 rb = sortedBoxes[(size_t)b * SORT_N + r];
    float rarea = (rb.z - rb.x) * (rb.w - rb.y);
    unsigned long long word = 0ull;
    for (int c = 0; c < 64; ++c) {
        int j = cc * 64 + c;
        float4 cb = colb[c];
        float carea = (cb.z - cb.x) * (cb.w - cb.y);
        float ltx = fmaxf(rb.x, cb.x);
        float lty = fmaxf(rb.y, cb.y);
        float rbx = fminf(rb.z, cb.z);
        float rby = fminf(rb.w, cb.w);
        float iw = fmaxf(rbx - ltx, 0.0f);
        float ih = fmaxf(rby - lty, 0.0f);
        float inter = iw * ih;
        float iou = inter / (rarea + carea - inter + 1e-9f);
        if (iou > NMS_TH && j > r) word |= (1ull << c);
    }
    colmaj[((size_t)b * MASK_WORDS + cc) * SORT_N + r] = word;   // coalesced
    rowmaj[((size_t)b * SORT_N + r) * MASK_WORDS + cc] = word;   // scatter
}

// ---------------------------------------------------------------------------
// Kernel F: group-tile greedy scan — INLINE-ASM pipelined loads.
// Plain-HIP attempts failed twice (scratch demotion r0/r1; MachineSink load
// collapse r2, VGPR=60). Now every in-loop global load is a volatile asm
// global_load_dwordx2 (volatile asm keeps program order among itself, cannot
// be sunk), waits are hand-counted s_waitcnt vmcnt(N) (never 0 in the loop)
// + sched_barrier(0) fences (rule 18).
// Schedule (3-slot modulo, unroll x3): per step g with slot X:
//   [wait vmcnt(W)]  -> K_X(g-3) and P_X(g) complete (issued 3 steps ago)
//   retire: rem |= OR16(K_X) (if valid)
//   decision for group g using pd_X (diag) + carries d1c/e2c
//   issue 16 K_X(g) loads (rowmaj, coalesced; padded to static count)
//   issue 3 P_X(g+3) loads (colmaj diag/col+1/col+2)
// Steady-state W = 2*(16+3) = 38. Retire(g) covers rows <= g-3, so only
// distance-1/2 carries are needed (col3/e3c machinery deleted).
// ---------------------------------------------------------------------------
__device__ inline unsigned long long rl64(unsigned long long v, int src) {
    unsigned lo = (unsigned)__builtin_amdgcn_readlane((int)(unsigned)(v & 0xFFFFFFFFull), src);
    unsigned hi = (unsigned)__builtin_amdgcn_readlane((int)(unsigned)(v >> 32), src);
    return ((unsigned long long)hi << 32) | lo;
}

#define GLOAD(dst, addr) \
    asm volatile("global_load_dwordx2 %0, %1, off" : "=v"(dst) : "v"(addr))
#define WAITV(n) asm volatile("s_waitcnt vmcnt(" #n ")" ::: "memory")
#define SCHED0 __builtin_amdgcn_sched_barrier(0)

#define OR16(P) (((((P##0 | P##1) | (P##2 | P##3)) | ((P##4 | P##5) | (P##6 | P##7))) | \
                  (((P##8 | P##9) | (P##10 | P##11)) | ((P##12 | P##13) | (P##14 | P##15)))))

#define EXTN(ik) int ik = am2 ? __builtin_ctzll(am2) : i0; am2 = am2 ? (am2 & (am2 - 1)) : 0ull;

#define NMS_STEP(X, G, W)                                                      \
    if (!done) {                                                               \
        const int g_ = (G);                                                    \
        WAITV(W);                                                              \
        SCHED0;                                                                \
        if (v##X) rem |= OR16(q##X) | ovf##X;                                  \
        v##X = false; ovf##X = 0ull;                                           \
        unsigned long long cur = rl64(rem, g_) | d1c | e2c;                    \
        unsigned long long pending = ~cur;                                     \
        unsigned long long alive = 0ull;                                       \
        unsigned long long Dg = pd##X;                                         \
        while (pending) {                                                      \
            int bit = __builtin_ctzll(pending);                                \
            if (lane == 0) kept[kcnt] = (g_ << 6) + bit;                       \
            ++kcnt;                                                            \
            alive |= 1ull << bit;                                              \
            if (kcnt == POST_NMS) { done = true; break; }                      \
            unsigned long long d = rl64(Dg, bit);                              \
            pending &= ~(d | (1ull << bit));                                   \
        }                                                                      \
        if (!done) {                                                           \
            unsigned long long s1 = 0, s2 = 0;                                 \
            unsigned long long am = alive;                                     \
            while (am) {                                                       \
                int i = __builtin_ctzll(am); am &= am - 1;                     \
                s1 |= rl64(p1##X, i); s2 |= rl64(p2##X, i);                    \
            }                                                                  \
            e2c = u2a; u2a = s2; d1c = s1;                                     \
            unsigned long long am2 = alive ? alive : 1ull;                     \
            int i0 = __builtin_ctzll(am2); am2 &= am2 - 1;                     \
            EXTN(i1)  EXTN(i2)  EXTN(i3)  EXTN(i4)  EXTN(i5)                   \
            EXTN(i6)  EXTN(i7)  EXTN(i8)  EXTN(i9)  EXTN(i10)                  \
            EXTN(i11) EXTN(i12) EXTN(i13) EXTN(i14) EXTN(i15)                  \
            const unsigned long long* bR =                                     \
                R + ((size_t)g_ << 6) * MASK_WORDS + lane;                     \
            GLOAD(q##X##0,  bR + (size_t)i0  * MASK_WORDS);                    \
            GLOAD(q##X##1,  bR + (size_t)i1  * MASK_WORDS);                    \
            GLOAD(q##X##2,  bR + (size_t)i2  * MASK_WORDS);                    \
            GLOAD(q##X##3,  bR + (size_t)i3  * MASK_WORDS);                    \
            GLOAD(q##X##4,  bR + (size_t)i4  * MASK_WORDS);                    \
            GLOAD(q##X##5,  bR + (size_t)i5  * MASK_WORDS);                    \
            GLOAD(q##X##6,  bR + (size_t)i6  * MASK_WORDS);                    \
            GLOAD(q##X##7,  bR + (size_t)i7  * MASK_WORDS);                    \
            GLOAD(q##X##8,  bR + (size_t)i8  * MASK_WORDS);                    \
            GLOAD(q##X##9,  bR + (size_t)i9  * MASK_WORDS);                    \
            GLOAD(q##X##10, bR + (size_t)i10 * MASK_WORDS);                    \
            GLOAD(q##X##11, bR + (size_t)i11 * MASK_WORDS);                    \
            GLOAD(q##X##12, bR + (size_t)i12 * MASK_WORDS);                    \
            GLOAD(q##X##13, bR + (size_t)i13 * MASK_WORDS);                    \
            GLOAD(q##X##14, bR + (size_t)i14 * MASK_WORDS);                    \
            GLOAD(q##X##15, bR + (size_t)i15 * MASK_WORDS);                    \
            v##X = (alive != 0ull);                                            \
            while (am2) { /* >16 kept: rare; compiler load+wait (safe drain) */\
                int jx = __builtin_ctzll(am2); am2 &= am2 - 1;                 \
                ovf##X |= bR[(size_t)jx * MASK_WORDS];                         \
            }                                                                  \
            GLOAD(pd##X, C + (size_t)(g_ + 3) * SORT_N + ((size_t)(g_ + 3) << 6) + lane); \
            GLOAD(p1##X, C + (size_t)(g_ + 4) * SORT_N + ((size_t)(g_ + 3) << 6) + lane); \
            GLOAD(p2##X, C + (size_t)(g_ + 5) * SORT_N + ((size_t)(g_ + 3) << 6) + lane); \
        }                                                                      \
    }

__global__ __launch_bounds__(64, 1) void nms_scan_kernel(
    const unsigned long long* __restrict__ colmaj,
    const unsigned long long* __restrict__ rowmaj,
    const float4* __restrict__ sortedBoxes,
    float* __restrict__ out) {
    int b = blockIdx.x;
    int lane = threadIdx.x;  // 0..63
    const unsigned long long* C = colmaj + (size_t)b * MASK_WORDS * SORT_N;
    const unsigned long long* R = rowmaj + (size_t)b * SORT_N * MASK_WORDS;
    __shared__ int kept[POST_NMS];

    unsigned long long rem = 0ull;  // lane w: removed bits of group w
    // three K generations, 16 named u64 each — written ONLY by asm loads
    unsigned long long qA0=0,qA1=0,qA2=0,qA3=0,qA4=0,qA5=0,qA6=0,qA7=0,
                       qA8=0,qA9=0,qA10=0,qA11=0,qA12=0,qA13=0,qA14=0,qA15=0;
    unsigned long long qB0=0,qB1=0,qB2=0,qB3=0,qB4=0,qB5=0,qB6=0,qB7=0,
                       qB8=0,qB9=0,qB10=0,qB11=0,qB12=0,qB13=0,qB14=0,qB15=0;
    unsigned long long qC0=0,qC1=0,qC2=0,qC3=0,qC4=0,qC5=0,qC6=0,qC7=0,
                       qC8=0,qC9=0,qC10=0,qC11=0,qC12=0,qC13=0,qC14=0,qC15=0;
    unsigned long long pdA=0,p1A=0,p2A=0, pdB=0,p1B=0,p2B=0, pdC=0,p1C=0,p2C=0;
    bool vA=false, vB=false, vC=false;
    unsigned long long ovfA=0, ovfB=0, ovfC=0;
    unsigned long long d1c=0, e2c=0, u2a=0;
    int kcnt = 0;
    bool done = false;

    // prologue: issue P for groups 0,1,2 (3 loads each; chronological order!)
    GLOAD(pdA, C + (size_t)0 * SORT_N +   0 + lane);
    GLOAD(p1A, C + (size_t)1 * SORT_N +   0 + lane);
    GLOAD(p2A, C + (size_t)2 * SORT_N +   0 + lane);
    GLOAD(pdB, C + (size_t)1 * SORT_N +  64 + lane);
    GLOAD(p1B, C + (size_t)2 * SORT_N +  64 + lane);
    GLOAD(p2B, C + (size_t)3 * SORT_N +  64 + lane);
    GLOAD(pdC, C + (size_t)2 * SORT_N + 128 + lane);
    GLOAD(p1C, C + (size_t)3 * SORT_N + 128 + lane);
    GLOAD(p2C, C + (size_t)4 * SORT_N + 128 + lane);

    // waits: step0 completes P_A (6 younger), step1 P_B (22 younger),
    // step2 onward steady-state 38 = K(16)+P(3) x 2 younger generations.
    NMS_STEP(A, 0, 6)
    NMS_STEP(B, 1, 22)
    NMS_STEP(C, 2, 38)
    for (int gg = 3; gg <= 60; gg += 3) {
        NMS_STEP(A, gg, 38)
        NMS_STEP(B, gg + 1, 38)
        NMS_STEP(C, gg + 2, 38)
        if (done) break;
    }
    NMS_STEP(A, 63, 38)

    WAITV(0);   // drain outstanding asm loads before epilogue
    SCHED0;

    __syncthreads();
    for (int r = lane; r < POST_NMS; r += 64) {
        float* o = out + ((size_t)b * POST_NMS + r) * 5;
        float4 bx = make_float4(0.f, 0.f, 0.f, 0.f);
        if (r < kcnt) bx = sortedBoxes[(size_t)b * SORT_N + kept[r]];
        o[0] = (float)b;
        o[1] = bx.x;
        o[2] = bx.y;
        o[3] = bx.z;
        o[4] = bx.w;
    }
}

// ---------------------------------------------------------------------------
extern "C" void kernel_launch(void* const* d_in, const int* in_sizes, int n_in,
                              void* d_out, int out_size, void* d_ws, size_t ws_size,
                              hipStream_t stream) {
    const float* scores  = (const float*)d_in[0];
    const float* deltas  = (const float*)d_in[1];
    const float* im_info = (const float*)d_in[2];
    const float* anchors = (const float*)d_in[3];
    float* out = (float*)d_out;

    char* ws = (char*)d_ws;
    size_t off = 0;
    float4* boxes = (float4*)(ws + off);
    off += (size_t)B_N * N_PROP * sizeof(float4);
    off = (off + 255) & ~(size_t)255;
    unsigned long long* keys = (unsigned long long*)(ws + off);
    off += (size_t)B_N * N_PROP * sizeof(unsigned long long);
    off = (off + 255) & ~(size_t)255;
    float4* sortedBoxes = (float4*)(ws + off);
    off += (size_t)B_N * SORT_N * sizeof(float4);
    off = (off + 255) & ~(size_t)255;
    unsigned long long* colmaj = (unsigned long long*)(ws + off);
    off += (size_t)B_N * MASK_WORDS * SORT_N * sizeof(unsigned long long);
    off = (off + 255) & ~(size_t)255;
    unsigned long long* rowmaj = (unsigned long long*)(ws + off);
    off += (size_t)B_N * SORT_N * MASK_WORDS * sizeof(unsigned long long);
    off = (off + 255) & ~(size_t)255;
    unsigned long long* cand = (unsigned long long*)(ws + off);
    off += (size_t)B_N * CAND_MAX * sizeof(unsigned long long);
    off = (off + 255) & ~(size_t)255;
    unsigned* ghist = (unsigned*)(ws + off);
    size_t zero_off = off;
    off += (size_t)B_N * NBINS * sizeof(unsigned);
    unsigned* cnt = (unsigned*)(ws + off);
    off += (size_t)B_N * sizeof(unsigned);
    size_t zero_bytes = off - zero_off;
    off = (off + 255) & ~(size_t)255;
    int* Tbuf = (int*)(ws + off);
    off += (size_t)B_N * sizeof(int);

    hipMemsetAsync((void*)ghist, 0, zero_bytes, stream);

    int total = B_N * N_PROP;
    decode_kernel<<<(total + 255) / 256, 256, 0, stream>>>(
        scores, deltas, im_info, anchors, boxes, keys, ghist);
    findT_kernel<<<B_N, 64, 0, stream>>>(ghist, Tbuf);
    compact_kernel<<<dim3((N_PROP + 255) / 256, B_N), 256, 0, stream>>>(
        keys, Tbuf, cnt, cand);
    rank_scatter_kernel<<<dim3(CAND_MAX / 64, B_N), 256, 0, stream>>>(
        cand, cnt, boxes, sortedBoxes);
    iou_mask_kernel<<<dim3(64, 64, B_N), 64, 0, stream>>>(sortedBoxes, colmaj, rowmaj);
    nms_scan_kernel<<<B_N, 64, 0, stream>>>(colmaj, rowmaj, sortedBoxes, out);
}

// Round 4
// 285.716 us; speedup vs baseline: 1.1262x; 1.0947x over previous
//
#include <hip/hip_runtime.h>
#include <stdint.h>

#define A_N 9
#define H_N 50
#define W_N 76
#define HW_N (H_N * W_N)      // 3800
#define N_PROP (A_N * HW_N)   // 34200
#define B_N 4
#define PRE_NMS 4000
#define POST_NMS 300
#define NMS_TH 0.7f
#define SORT_N 4096
#define MASK_WORDS 64
#define CAND_MAX 5120
#define NBINS 4096

// ---------------------------------------------------------------------------
// Kernel A: decode + keys (a-major mapping -> all loads/stores coalesced).
// ---------------------------------------------------------------------------
__global__ void decode_kernel(const float* __restrict__ scores,
                              const float* __restrict__ deltas,
                              const float* __restrict__ im_info,
                              const float* __restrict__ anchors,
                              float4* __restrict__ boxes,
                              unsigned long long* __restrict__ keys,
                              unsigned* __restrict__ ghist) {
#pragma clang fp contract(off)
    int gid = blockIdx.x * blockDim.x + threadIdx.x;
    if (gid >= B_N * N_PROP) return;
    int b = gid / N_PROP;
    int r = gid - b * N_PROP;
    int a = r / HW_N;          // fixed across a wave
    int hw = r - a * HW_N;     // consecutive across lanes
    int hy = hw / W_N;
    int wx = hw - hy * W_N;

    float sx = (float)wx * 16.0f;
    float sy = (float)hy * 16.0f;
    float ax1 = anchors[a * 4 + 0] + sx;
    float ay1 = anchors[a * 4 + 1] + sy;
    float ax2 = anchors[a * 4 + 2] + sx;
    float ay2 = anchors[a * 4 + 3] + sy;
    float aw = ax2 - ax1 + 1.0f;
    float ah = ay2 - ay1 + 1.0f;
    float cx = ax1 + 0.5f * aw;
    float cy = ay1 + 0.5f * ah;

    const float* db = deltas + ((size_t)b * 36 + (size_t)a * 4) * HW_N + hw;
    float d0 = db[0];
    float d1 = db[HW_N];
    float d2 = db[2 * HW_N];
    float d3 = db[3 * HW_N];

    float pcx = d0 * aw + cx;
    float pcy = d1 * ah + cy;
    float pw  = expf(d2) * aw;
    float ph  = expf(d3) * ah;

    float x1 = pcx - 0.5f * pw;
    float y1 = pcy - 0.5f * ph;
    float x2 = pcx + 0.5f * pw;
    float y2 = pcy + 0.5f * ph;

    float xhi = im_info[b * 3 + 1] - 1.0f;
    float yhi = im_info[b * 3 + 0] - 1.0f;
    x1 = fminf(fmaxf(x1, 0.0f), xhi);
    y1 = fminf(fmaxf(y1, 0.0f), yhi);
    x2 = fminf(fmaxf(x2, 0.0f), xhi);
    y2 = fminf(fmaxf(y2, 0.0f), yhi);

    boxes[gid] = make_float4(x1, y1, x2, y2);  // a-major layout

    float s = scores[((size_t)b * A_N + a) * HW_N + hw];
    unsigned f = __float_as_uint(s);
    unsigned sk = f ^ ((f & 0x80000000u) ? 0xFFFFFFFFu : 0x80000000u);
    unsigned n_ref = (unsigned)(hw * A_N + a);
    unsigned long long key = ((unsigned long long)sk << 32) | (unsigned)(~n_ref);
    keys[gid] = key;
    atomicAdd(&ghist[b * NBINS + (unsigned)(key >> 52)], 1u);
}

// ---------------------------------------------------------------------------
// Kernel B: threshold bucket T via two wave-level suffix scans.
// ---------------------------------------------------------------------------
__global__ __launch_bounds__(64) void findT_kernel(const unsigned* __restrict__ ghist,
                                                   int* __restrict__ Tout) {
    __shared__ unsigned h[NBINS];
    int b = blockIdx.x;
    int lane = threadIdx.x;  // 64
    for (int i = lane; i < NBINS; i += 64) h[i] = ghist[b * NBINS + i];
    __syncthreads();
    unsigned gsum = 0;
    for (int j = 0; j < 64; ++j) gsum += h[lane * 64 + j];
    unsigned s = gsum;
    for (int d = 1; d < 64; d <<= 1) {
        unsigned t = (unsigned)__shfl_down((int)s, d);
        if (lane + d < 64) s += t;
    }
    unsigned long long bal = __ballot(s >= PRE_NMS);
    int gstar = 63 - __builtin_clzll(bal);
    unsigned after = (gstar < 63) ? (unsigned)__builtin_amdgcn_readlane((int)s, gstar + 1) : 0u;
    unsigned R = PRE_NMS - after;
    unsigned s2 = h[gstar * 64 + lane];
    for (int d = 1; d < 64; d <<= 1) {
        unsigned t = (unsigned)__shfl_down((int)s2, d);
        if (lane + d < 64) s2 += t;
    }
    unsigned long long bal2 = __ballot(s2 >= R);
    int j = 63 - __builtin_clzll(bal2);
    if (lane == 0) Tout[b] = gstar * 64 + j;
}

// ---------------------------------------------------------------------------
// Kernel C: compact candidates; wave-aggregated atomic.
// ---------------------------------------------------------------------------
__global__ void compact_kernel(const unsigned long long* __restrict__ keys,
                               const int* __restrict__ T,
                               unsigned* __restrict__ cnt,
                               unsigned long long* __restrict__ cand) {
    int b = blockIdx.y;
    int n = blockIdx.x * 256 + threadIdx.x;
    bool pred = false;
    unsigned long long k = 0ull;
    if (n < N_PROP) {
        k = keys[(size_t)b * N_PROP + n];
        pred = ((int)(unsigned)(k >> 52) >= T[b]);
    }
    unsigned long long m = __ballot(pred);
    if (m) {
        int lane = threadIdx.x & 63;
        int lead = __ffsll((unsigned long long)m) - 1;
        unsigned base = 0;
        if (lane == lead) base = atomicAdd(&cnt[b], (unsigned)__popcll(m));
        base = __shfl((int)base, lead);
        if (pred) {
            unsigned pos = base + (unsigned)__popcll(m & ((1ull << lane) - 1ull));
            if (pos < CAND_MAX) cand[(size_t)b * CAND_MAX + pos] = k;
        }
    }
}

// ---------------------------------------------------------------------------
// Kernel D: exact rank by pairwise count, 4-way j-split per candidate.
// ---------------------------------------------------------------------------
__global__ __launch_bounds__(256) void rank_scatter_kernel(
    const unsigned long long* __restrict__ cand,
    const unsigned* __restrict__ cnt,
    const float4* __restrict__ boxes,
    float4* __restrict__ sortedBoxes) {
    __shared__ unsigned long long sk[256];
    int b = blockIdx.y;
    int tid = threadIdx.x;
    int ci = blockIdx.x * 64 + (tid >> 2);
    int q = tid & 3;
    int mc = (int)min(cnt[b], (unsigned)CAND_MAX);
    unsigned long long my = (ci < mc) ? cand[(size_t)b * CAND_MAX + ci] : 0ull;
    int rank = 0;
    int nt = (mc + 255) >> 8;
    for (int t = 0; t < nt; ++t) {
        int j = t * 256 + tid;
        sk[tid] = (j < mc) ? cand[(size_t)b * CAND_MAX + j] : 0ull;
        __syncthreads();
#pragma unroll 16
        for (int c = 0; c < 64; ++c) {
            int cc = q * 64 + ((c + q * 17) & 63);  // stagger: avoid 4-way bank conflict
            rank += (sk[cc] > my) ? 1 : 0;
        }
        __syncthreads();
    }
    rank += __shfl_xor(rank, 1);
    rank += __shfl_xor(rank, 2);
    if (q == 0 && ci < mc && rank < PRE_NMS) {
        unsigned n_ref = ~(unsigned)(my & 0xFFFFFFFFull);
        unsigned a = n_ref % A_N;
        unsigned hw = n_ref / A_N;
        sortedBoxes[(size_t)b * SORT_N + rank] =
            boxes[(size_t)b * N_PROP + a * HW_N + hw];
    }
    if (q == 1) {
        int pi = blockIdx.x * 64 + (tid >> 2);
        if (pi >= PRE_NMS && pi < SORT_N)
            sortedBoxes[(size_t)b * SORT_N + pi] = make_float4(0.f, 0.f, 0.f, 0.f);
    }
}

// ---------------------------------------------------------------------------
// Kernel E: suppression bitmask -> TWO layouts:
//   colmaj[cc*SORT_N + r]  (coalesced store; decider's diag/col reads)
//   rowmaj[r*64 + cc]      (scatter store; loader waves' row reads COALESCED)
// ---------------------------------------------------------------------------
__global__ void iou_mask_kernel(const float4* __restrict__ sortedBoxes,
                                unsigned long long* __restrict__ colmaj,
                                unsigned long long* __restrict__ rowmaj) {
#pragma clang fp contract(off)
    int rc = blockIdx.x, cc = blockIdx.y, b = blockIdx.z;
    if (cc < rc) return;
    int t = threadIdx.x;
    __shared__ float4 colb[64];
    colb[t] = sortedBoxes[(size_t)b * SORT_N + cc * 64 + t];
    __syncthreads();
    int r = rc * 64 + t;
    float4 rb = sortedBoxes[(size_t)b * SORT_N + r];
    float rarea = (rb.z - rb.x) * (rb.w - rb.y);
    unsigned long long word = 0ull;
    for (int c = 0; c < 64; ++c) {
        int j = cc * 64 + c;
        float4 cb = colb[c];
        float carea = (cb.z - cb.x) * (cb.w - cb.y);
        float ltx = fmaxf(rb.x, cb.x);
        float lty = fmaxf(rb.y, cb.y);
        float rbx = fminf(rb.z, cb.z);
        float rby = fminf(rb.w, cb.w);
        float iw = fmaxf(rbx - ltx, 0.0f);
        float ih = fmaxf(rby - lty, 0.0f);
        float inter = iw * ih;
        float iou = inter / (rarea + carea - inter + 1e-9f);
        if (iou > NMS_TH && j > r) word |= (1ull << c);
    }
    colmaj[((size_t)b * MASK_WORDS + cc) * SORT_N + r] = word;   // coalesced
    rowmaj[((size_t)b * SORT_N + r) * MASK_WORDS + cc] = word;   // scatter
}

// ---------------------------------------------------------------------------
// Kernel F: MULTI-WAVE greedy scan (producer/consumer via LDS, defer = 2).
//
// 3 rounds of evidence: compiler destroys cross-iteration register pipelines
// (r0/r1 scratch demotion, r2 MachineSink collapse VGPR=60, r3 asm-output
// spill VGPR=64 -> serialized load/wait/spill = 95.8us). So: NO register
// pipeline. Wave 0 = decider; waves 1-3 = loaders folding kept rows into an
// LDS rem[] (atomicOr). All loads are intra-iteration straight-line batches
// -> nothing for the compiler to sink or spill.
//
// Ordering (barrier-exact):
//  - iter g: wave0 decides group g from remLds[g] | d1c; publishes alive[g].
//  - iter g+1: loaders read alive[g], load the kept rows (rowmaj, coalesced
//    512B/row), OR into remLds; ds ops complete before the iter barrier.
//  - iter g+2: wave0's read of remLds[g+2] sees them. The distance-1 gap is
//    exactly d1c (readlane carry from prefetched col word g+1 over rows g).
//  - races: loaders at iter g write word g only with bits that are a subset
//    of d1c (idempotent OR, benign). Lower-tri poison words of a row in
//    group g-1 are words w <= g-1, read at iters <= g-1, strictly before the
//    fold at iter g (barrier-ordered). All other folded words are upper-tri.
// ---------------------------------------------------------------------------
__device__ inline unsigned long long rl64(unsigned long long v, int src) {
    unsigned lo = (unsigned)__builtin_amdgcn_readlane((int)(unsigned)(v & 0xFFFFFFFFull), src);
    unsigned hi = (unsigned)__builtin_amdgcn_readlane((int)(unsigned)(v >> 32), src);
    return ((unsigned long long)hi << 32) | lo;
}

#define EXTN(ik) int ik = am2 ? __builtin_ctzll(am2) : i0; am2 = am2 ? (am2 & (am2 - 1)) : 0ull;

__global__ __launch_bounds__(256, 1) void nms_scan_kernel(
    const unsigned long long* __restrict__ colmaj,
    const unsigned long long* __restrict__ rowmaj,
    const float4* __restrict__ sortedBoxes,
    float* __restrict__ out) {
    int b = blockIdx.x;
    int tid = threadIdx.x;
    int lane = tid & 63;
    int wv = tid >> 6;                 // 0 = decider, 1..3 = loaders
    const unsigned long long* C = colmaj + (size_t)b * MASK_WORDS * SORT_N;
    const unsigned long long* R = rowmaj + (size_t)b * SORT_N * MASK_WORDS;

    __shared__ int kept[POST_NMS];
    __shared__ unsigned remW[MASK_WORDS][2];          // [word][lo,hi]
    __shared__ unsigned long long aliveLds[MASK_WORDS];
    __shared__ int doneLds;
    __shared__ int kcntLds;

    if (tid < MASK_WORDS) { remW[tid][0] = 0u; remW[tid][1] = 0u; aliveLds[tid] = 0ull; }
    if (tid == 0) { doneLds = 0; kcntLds = 0; }
    __syncthreads();

    unsigned long long d1c = 0ull;   // wave0 only: suppression of group g by group g-1 kept
    int kcnt = 0;

    for (int g = 0; g < MASK_WORDS; ++g) {
        if (wv == 0) {
            // ---------------- decider: group g ----------------
            unsigned long long Dg = C[(size_t)g * SORT_N + ((size_t)g << 6) + lane];
            unsigned long long c1 = (g < 63)
                ? C[(size_t)(g + 1) * SORT_N + ((size_t)g << 6) + lane] : 0ull;
            unsigned long long rem_g =
                ((unsigned long long)remW[g][1] << 32) | (unsigned long long)remW[g][0];
            unsigned long long cur = rem_g | d1c;
            unsigned long long pending = ~cur;
            unsigned long long alive = 0ull;
            bool hit = false;
            while (pending) {
                int bit = __builtin_ctzll(pending);
                if (lane == 0) kept[kcnt] = (g << 6) + bit;
                ++kcnt;
                alive |= 1ull << bit;
                if (kcnt == POST_NMS) { hit = true; break; }
                unsigned long long d = rl64(Dg, bit);
                pending &= ~(d | (1ull << bit));
            }
            if (lane == 0) {
                aliveLds[g] = alive;
                kcntLds = kcnt;
                if (hit) doneLds = 1;
            }
            // distance-1 carry for group g+1
            unsigned long long s1 = 0ull;
            unsigned long long am = alive;
            while (am) {
                int i = __builtin_ctzll(am); am &= am - 1;
                s1 |= rl64(c1, i);
            }
            d1c = s1;
        } else if (g >= 1) {
            // ---------------- loaders: fold kept rows of group g-1 ----------------
            unsigned long long am = aliveLds[g - 1];
            unsigned long long myMask = 0ull;
            {   // round-robin partition of kept bits among waves 1..3
                unsigned long long t = am; int i = 0;
                while (t) {
                    int bb = __builtin_ctzll(t); t &= t - 1;
                    if ((i % 3) == (wv - 1)) myMask |= 1ull << bb;
                    ++i;
                }
            }
            if (myMask) {
                const unsigned long long* bR =
                    R + (((size_t)(g - 1)) << 6) * MASK_WORDS + lane;
                unsigned long long am2 = myMask;
                int i0 = __builtin_ctzll(am2); am2 &= am2 - 1;
                EXTN(i1) EXTN(i2) EXTN(i3) EXTN(i4) EXTN(i5) EXTN(i6) EXTN(i7)
                // straight-line batch: 8 loads, ONE wait, then OR (pads repeat i0)
                unsigned long long t0 = bR[(size_t)i0 * MASK_WORDS];
                unsigned long long t1 = bR[(size_t)i1 * MASK_WORDS];
                unsigned long long t2 = bR[(size_t)i2 * MASK_WORDS];
                unsigned long long t3 = bR[(size_t)i3 * MASK_WORDS];
                unsigned long long t4 = bR[(size_t)i4 * MASK_WORDS];
                unsigned long long t5 = bR[(size_t)i5 * MASK_WORDS];
                unsigned long long t6 = bR[(size_t)i6 * MASK_WORDS];
                unsigned long long t7 = bR[(size_t)i7 * MASK_WORDS];
                unsigned long long acc = ((t0 | t1) | (t2 | t3)) | ((t4 | t5) | (t6 | t7));
                while (am2) {   // >24 kept in one group: rare, serial
                    int j = __builtin_ctzll(am2); am2 &= am2 - 1;
                    acc |= bR[(size_t)j * MASK_WORDS];
                }
                unsigned lo = (unsigned)acc, hi = (unsigned)(acc >> 32);
                if (lo) atomicOr(&remW[lane][0], lo);
                if (hi) atomicOr(&remW[lane][1], hi);
            }
        }
        __syncthreads();
        if (doneLds) break;
    }

    int kc = kcntLds;   // last write barrier-ordered before every exit path
    for (int r = tid; r < POST_NMS; r += 256) {
        float* o = out + ((size_t)b * POST_NMS + r) * 5;
        float4 bx = make_float4(0.f, 0.f, 0.f, 0.f);
        if (r < kc) bx = sortedBoxes[(size_t)b * SORT_N + kept[r]];
        o[0] = (float)b;
        o[1] = bx.x;
        o[2] = bx.y;
        o[3] = bx.z;
        o[4] = bx.w;
    }
}

// ---------------------------------------------------------------------------
extern "C" void kernel_launch(void* const* d_in, const int* in_sizes, int n_in,
                              void* d_out, int out_size, void* d_ws, size_t ws_size,
                              hipStream_t stream) {
    const float* scores  = (const float*)d_in[0];
    const float* deltas  = (const float*)d_in[1];
    const float* im_info = (const float*)d_in[2];
    const float* anchors = (const float*)d_in[3];
    float* out = (float*)d_out;

    char* ws = (char*)d_ws;
    size_t off = 0;
    float4* boxes = (float4*)(ws + off);
    off += (size_t)B_N * N_PROP * sizeof(float4);
    off = (off + 255) & ~(size_t)255;
    unsigned long long* keys = (unsigned long long*)(ws + off);
    off += (size_t)B_N * N_PROP * sizeof(unsigned long long);
    off = (off + 255) & ~(size_t)255;
    float4* sortedBoxes = (float4*)(ws + off);
    off += (size_t)B_N * SORT_N * sizeof(float4);
    off = (off + 255) & ~(size_t)255;
    unsigned long long* colmaj = (unsigned long long*)(ws + off);
    off += (size_t)B_N * MASK_WORDS * SORT_N * sizeof(unsigned long long);
    off = (off + 255) & ~(size_t)255;
    unsigned long long* rowmaj = (unsigned long long*)(ws + off);
    off += (size_t)B_N * SORT_N * MASK_WORDS * sizeof(unsigned long long);
    off = (off + 255) & ~(size_t)255;
    unsigned long long* cand = (unsigned long long*)(ws + off);
    off += (size_t)B_N * CAND_MAX * sizeof(unsigned long long);
    off = (off + 255) & ~(size_t)255;
    unsigned* ghist = (unsigned*)(ws + off);
    size_t zero_off = off;
    off += (size_t)B_N * NBINS * sizeof(unsigned);
    unsigned* cnt = (unsigned*)(ws + off);
    off += (size_t)B_N * sizeof(unsigned);
    size_t zero_bytes = off - zero_off;
    off = (off + 255) & ~(size_t)255;
    int* Tbuf = (int*)(ws + off);
    off += (size_t)B_N * sizeof(int);

    hipMemsetAsync((void*)ghist, 0, zero_bytes, stream);

    int total = B_N * N_PROP;
    decode_kernel<<<(total + 255) / 256, 256, 0, stream>>>(
        scores, deltas, im_info, anchors, boxes, keys, ghist);
    findT_kernel<<<B_N, 64, 0, stream>>>(ghist, Tbuf);
    compact_kernel<<<dim3((N_PROP + 255) / 256, B_N), 256, 0, stream>>>(
        keys, Tbuf, cnt, cand);
    rank_scatter_kernel<<<dim3(CAND_MAX / 64, B_N), 256, 0, stream>>>(
        cand, cnt, boxes, sortedBoxes);
    iou_mask_kernel<<<dim3(64, 64, B_N), 64, 0, stream>>>(sortedBoxes, colmaj, rowmaj);
    nms_scan_kernel<<<B_N, 256, 0, stream>>>(colmaj, rowmaj, sortedBoxes, out);
}

// Round 5
// 285.637 us; speedup vs baseline: 1.1265x; 1.0003x over previous
//
#include <hip/hip_runtime.h>
#include <stdint.h>

#define A_N 9
#define H_N 50
#define W_N 76
#define HW_N (H_N * W_N)      // 3800
#define N_PROP (A_N * HW_N)   // 34200
#define B_N 4
#define PRE_NMS 4000
#define POST_NMS 300
#define NMS_TH 0.7f
#define SORT_N 4096
#define MASK_WORDS 64
#define CAND_MAX 5120
#define NBINS 4096

// ---------------------------------------------------------------------------
// Kernel A: decode + keys (a-major mapping -> all loads/stores coalesced).
// ---------------------------------------------------------------------------
__global__ void decode_kernel(const float* __restrict__ scores,
                              const float* __restrict__ deltas,
                              const float* __restrict__ im_info,
                              const float* __restrict__ anchors,
                              float4* __restrict__ boxes,
                              unsigned long long* __restrict__ keys,
                              unsigned* __restrict__ ghist) {
#pragma clang fp contract(off)
    int gid = blockIdx.x * blockDim.x + threadIdx.x;
    if (gid >= B_N * N_PROP) return;
    int b = gid / N_PROP;
    int r = gid - b * N_PROP;
    int a = r / HW_N;          // fixed across a wave
    int hw = r - a * HW_N;     // consecutive across lanes
    int hy = hw / W_N;
    int wx = hw - hy * W_N;

    float sx = (float)wx * 16.0f;
    float sy = (float)hy * 16.0f;
    float ax1 = anchors[a * 4 + 0] + sx;
    float ay1 = anchors[a * 4 + 1] + sy;
    float ax2 = anchors[a * 4 + 2] + sx;
    float ay2 = anchors[a * 4 + 3] + sy;
    float aw = ax2 - ax1 + 1.0f;
    float ah = ay2 - ay1 + 1.0f;
    float cx = ax1 + 0.5f * aw;
    float cy = ay1 + 0.5f * ah;

    const float* db = deltas + ((size_t)b * 36 + (size_t)a * 4) * HW_N + hw;
    float d0 = db[0];
    float d1 = db[HW_N];
    float d2 = db[2 * HW_N];
    float d3 = db[3 * HW_N];

    float pcx = d0 * aw + cx;
    float pcy = d1 * ah + cy;
    float pw  = expf(d2) * aw;
    float ph  = expf(d3) * ah;

    float x1 = pcx - 0.5f * pw;
    float y1 = pcy - 0.5f * ph;
    float x2 = pcx + 0.5f * pw;
    float y2 = pcy + 0.5f * ph;

    float xhi = im_info[b * 3 + 1] - 1.0f;
    float yhi = im_info[b * 3 + 0] - 1.0f;
    x1 = fminf(fmaxf(x1, 0.0f), xhi);
    y1 = fminf(fmaxf(y1, 0.0f), yhi);
    x2 = fminf(fmaxf(x2, 0.0f), xhi);
    y2 = fminf(fmaxf(y2, 0.0f), yhi);

    boxes[gid] = make_float4(x1, y1, x2, y2);  // a-major layout

    float s = scores[((size_t)b * A_N + a) * HW_N + hw];
    unsigned f = __float_as_uint(s);
    unsigned sk = f ^ ((f & 0x80000000u) ? 0xFFFFFFFFu : 0x80000000u);
    unsigned n_ref = (unsigned)(hw * A_N + a);
    unsigned long long key = ((unsigned long long)sk << 32) | (unsigned)(~n_ref);
    keys[gid] = key;
    atomicAdd(&ghist[b * NBINS + (unsigned)(key >> 52)], 1u);
}

// ---------------------------------------------------------------------------
// Kernel B: threshold bucket T via two wave-level suffix scans.
// ---------------------------------------------------------------------------
__global__ __launch_bounds__(64) void findT_kernel(const unsigned* __restrict__ ghist,
                                                   int* __restrict__ Tout) {
    __shared__ unsigned h[NBINS];
    int b = blockIdx.x;
    int lane = threadIdx.x;  // 64
    for (int i = lane; i < NBINS; i += 64) h[i] = ghist[b * NBINS + i];
    __syncthreads();
    unsigned gsum = 0;
    for (int j = 0; j < 64; ++j) gsum += h[lane * 64 + j];
    unsigned s = gsum;
    for (int d = 1; d < 64; d <<= 1) {
        unsigned t = (unsigned)__shfl_down((int)s, d);
        if (lane + d < 64) s += t;
    }
    unsigned long long bal = __ballot(s >= PRE_NMS);
    int gstar = 63 - __builtin_clzll(bal);
    unsigned after = (gstar < 63) ? (unsigned)__builtin_amdgcn_readlane((int)s, gstar + 1) : 0u;
    unsigned R = PRE_NMS - after;
    unsigned s2 = h[gstar * 64 + lane];
    for (int d = 1; d < 64; d <<= 1) {
        unsigned t = (unsigned)__shfl_down((int)s2, d);
        if (lane + d < 64) s2 += t;
    }
    unsigned long long bal2 = __ballot(s2 >= R);
    int j = 63 - __builtin_clzll(bal2);
    if (lane == 0) Tout[b] = gstar * 64 + j;
}

// ---------------------------------------------------------------------------
// Kernel C: compact candidates; wave-aggregated atomic.
// ---------------------------------------------------------------------------
__global__ void compact_kernel(const unsigned long long* __restrict__ keys,
                               const int* __restrict__ T,
                               unsigned* __restrict__ cnt,
                               unsigned long long* __restrict__ cand) {
    int b = blockIdx.y;
    int n = blockIdx.x * 256 + threadIdx.x;
    bool pred = false;
    unsigned long long k = 0ull;
    if (n < N_PROP) {
        k = keys[(size_t)b * N_PROP + n];
        pred = ((int)(unsigned)(k >> 52) >= T[b]);
    }
    unsigned long long m = __ballot(pred);
    if (m) {
        int lane = threadIdx.x & 63;
        int lead = __ffsll((unsigned long long)m) - 1;
        unsigned base = 0;
        if (lane == lead) base = atomicAdd(&cnt[b], (unsigned)__popcll(m));
        base = __shfl((int)base, lead);
        if (pred) {
            unsigned pos = base + (unsigned)__popcll(m & ((1ull << lane) - 1ull));
            if (pos < CAND_MAX) cand[(size_t)b * CAND_MAX + pos] = k;
        }
    }
}

// ---------------------------------------------------------------------------
// Kernel D: exact rank by pairwise count, 4-way j-split per candidate.
// ---------------------------------------------------------------------------
__global__ __launch_bounds__(256) void rank_scatter_kernel(
    const unsigned long long* __restrict__ cand,
    const unsigned* __restrict__ cnt,
    const float4* __restrict__ boxes,
    float4* __restrict__ sortedBoxes) {
    __shared__ unsigned long long sk[256];
    int b = blockIdx.y;
    int tid = threadIdx.x;
    int ci = blockIdx.x * 64 + (tid >> 2);
    int q = tid & 3;
    int mc = (int)min(cnt[b], (unsigned)CAND_MAX);
    unsigned long long my = (ci < mc) ? cand[(size_t)b * CAND_MAX + ci] : 0ull;
    int rank = 0;
    int nt = (mc + 255) >> 8;
    for (int t = 0; t < nt; ++t) {
        int j = t * 256 + tid;
        sk[tid] = (j < mc) ? cand[(size_t)b * CAND_MAX + j] : 0ull;
        __syncthreads();
#pragma unroll 16
        for (int c = 0; c < 64; ++c) {
            int cc = q * 64 + ((c + q * 17) & 63);  // stagger: avoid 4-way bank conflict
            rank += (sk[cc] > my) ? 1 : 0;
        }
        __syncthreads();
    }
    rank += __shfl_xor(rank, 1);
    rank += __shfl_xor(rank, 2);
    if (q == 0 && ci < mc && rank < PRE_NMS) {
        unsigned n_ref = ~(unsigned)(my & 0xFFFFFFFFull);
        unsigned a = n_ref % A_N;
        unsigned hw = n_ref / A_N;
        sortedBoxes[(size_t)b * SORT_N + rank] =
            boxes[(size_t)b * N_PROP + a * HW_N + hw];
    }
    if (q == 1) {
        int pi = blockIdx.x * 64 + (tid >> 2);
        if (pi >= PRE_NMS && pi < SORT_N)
            sortedBoxes[(size_t)b * SORT_N + pi] = make_float4(0.f, 0.f, 0.f, 0.f);
    }
}

// ---------------------------------------------------------------------------
// Kernel E: suppression bitmask -> TWO layouts:
//   colmaj[cc*SORT_N + r]  (coalesced store; prefetch waves' diag/col reads)
//   rowmaj[r*64 + cc]      (scatter store; loader waves' row reads COALESCED)
// ---------------------------------------------------------------------------
__global__ void iou_mask_kernel(const float4* __restrict__ sortedBoxes,
                                unsigned long long* __restrict__ colmaj,
                                unsigned long long* __restrict__ rowmaj) {
#pragma clang fp contract(off)
    int rc = blockIdx.x, cc = blockIdx.y, b = blockIdx.z;
    if (cc < rc) return;
    int t = threadIdx.x;
    __shared__ float4 colb[64];
    colb[t] = sortedBoxes[(size_t)b * SORT_N + cc * 64 + t];
    __syncthreads();
    int r = rc * 64 + t;
    float4 rb = sortedBoxes[(size_t)b * SORT_N + r];
    float rarea = (rb.z - rb.x) * (rb.w - rb.y);
    unsigned long long word = 0ull;
    for (int c = 0; c < 64; ++c) {
        int j = cc * 64 + c;
        float4 cb = colb[c];
        float carea = (cb.z - cb.x) * (cb.w - cb.y);
        float ltx = fmaxf(rb.x, cb.x);
        float lty = fmaxf(rb.y, cb.y);
        float rbx = fminf(rb.z, cb.z);
        float rby = fminf(rb.w, cb.w);
        float iw = fmaxf(rbx - ltx, 0.0f);
        float ih = fmaxf(rby - lty, 0.0f);
        float inter = iw * ih;
        float iou = inter / (rarea + carea - inter + 1e-9f);
        if (iou > NMS_TH && j > r) word |= (1ull << c);
    }
    colmaj[((size_t)b * MASK_WORDS + cc) * SORT_N + r] = word;   // coalesced
    rowmaj[((size_t)b * SORT_N + r) * MASK_WORDS + cc] = word;   // scatter
}

// ---------------------------------------------------------------------------
// Kernel F: MULTI-WAVE greedy scan, 8 waves, role-split (r4 structure + LDS
// prefetch ring for the decider's diag/col words).
//   wv0   = decider   : greedy chain; reads Dg/c1 from LDS ring (~30cy, was
//                       a ~500cy exposed global load under the barrier fence)
//   wv1-2 = prefetch  : parity-alternating; wave (1+(g&1)) stages
//                       {D(g+2), c1(g+2)} -> 4-slot LDS ring. Each has 2 full
//                       iterations of slack; zero cross-iteration registers
//                       (the thing r0-r3 proved the compiler destroys).
//   wv3-7 = loaders   : fold kept rows of g-1 into remW via LDS atomicOr
//                       (rowmaj, coalesced 512B/row; 5-way partition).
// Ordering identical to r4 (defer-2 + d1c carry):
//   decide(g) sees folds <= g-2 via remW + exact d1c for g-1. Prefetch slot
//   (g+2)&3 written at iter g, read at iter g+2 (2 barriers later); slot
//   reuse distance 4. Poison/lower-tri argument unchanged from r4.
// ---------------------------------------------------------------------------
__device__ inline unsigned long long rl64(unsigned long long v, int src) {
    unsigned lo = (unsigned)__builtin_amdgcn_readlane((int)(unsigned)(v & 0xFFFFFFFFull), src);
    unsigned hi = (unsigned)__builtin_amdgcn_readlane((int)(unsigned)(v >> 32), src);
    return ((unsigned long long)hi << 32) | lo;
}

#define EXTN(ik) int ik = am2 ? __builtin_ctzll(am2) : i0; am2 = am2 ? (am2 & (am2 - 1)) : 0ull;

__global__ __launch_bounds__(512, 1) void nms_scan_kernel(
    const unsigned long long* __restrict__ colmaj,
    const unsigned long long* __restrict__ rowmaj,
    const float4* __restrict__ sortedBoxes,
    float* __restrict__ out) {
    int b = blockIdx.x;
    int tid = threadIdx.x;
    int lane = tid & 63;
    int wv = tid >> 6;                 // 0=decider, 1-2=prefetch, 3-7=loaders
    const unsigned long long* C = colmaj + (size_t)b * MASK_WORDS * SORT_N;
    const unsigned long long* R = rowmaj + (size_t)b * SORT_N * MASK_WORDS;

    __shared__ int kept[POST_NMS];
    __shared__ unsigned remW[MASK_WORDS][2];          // [word][lo,hi]
    __shared__ unsigned long long aliveLds[MASK_WORDS];
    __shared__ unsigned long long bufD[4][64];        // prefetch ring: diag
    __shared__ unsigned long long bufC[4][64];        // prefetch ring: col g+1
    __shared__ int doneLds;
    __shared__ int kcntLds;

    if (tid < MASK_WORDS) { remW[tid][0] = 0u; remW[tid][1] = 0u; aliveLds[tid] = 0ull; }
    if (tid == 0) { doneLds = 0; kcntLds = 0; }
    // prologue: stage groups 0 and 1 into ring slots 0,1
    if (wv == 1) {
        bufD[0][lane] = C[(size_t)0 * SORT_N + 0 + lane];
        bufC[0][lane] = C[(size_t)1 * SORT_N + 0 + lane];
    }
    if (wv == 2) {
        bufD[1][lane] = C[(size_t)1 * SORT_N + 64 + lane];
        bufC[1][lane] = C[(size_t)2 * SORT_N + 64 + lane];
    }
    __syncthreads();

    unsigned long long d1c = 0ull;   // decider: suppression of group g by g-1 kept
    int kcnt = 0;

    for (int g = 0; g < MASK_WORDS; ++g) {
        if (wv == 0) {
            // ---------------- decider: group g (all inputs from LDS) --------
            unsigned long long Dg = bufD[g & 3][lane];
            unsigned long long c1 = bufC[g & 3][lane];
            unsigned long long rem_g =
                ((unsigned long long)remW[g][1] << 32) | (unsigned long long)remW[g][0];
            unsigned long long cur = rem_g | d1c;
            unsigned long long pending = ~cur;
            unsigned long long alive = 0ull;
            bool hit = false;
            while (pending) {
                int bit = __builtin_ctzll(pending);
                if (lane == 0) kept[kcnt] = (g << 6) + bit;
                ++kcnt;
                alive |= 1ull << bit;
                if (kcnt == POST_NMS) { hit = true; break; }
                unsigned long long d = rl64(Dg, bit);
                pending &= ~(d | (1ull << bit));
            }
            if (lane == 0) {
                aliveLds[g] = alive;
                kcntLds = kcnt;
                if (hit) doneLds = 1;
            }
            // distance-1 carry for group g+1
            unsigned long long s1 = 0ull;
            unsigned long long am = alive;
            while (am) {
                int i = __builtin_ctzll(am); am &= am - 1;
                s1 |= rl64(c1, i);
            }
            d1c = s1;
        } else if (wv == 1 + (g & 1)) {
            // ---------------- prefetch: stage group g+2 into the ring -------
            int gp = g + 2;
            if (gp < MASK_WORDS) {
                unsigned long long d = C[(size_t)gp * SORT_N + ((size_t)gp << 6) + lane];
                unsigned long long c = (gp + 1 < MASK_WORDS)
                    ? C[(size_t)(gp + 1) * SORT_N + ((size_t)gp << 6) + lane] : 0ull;
                bufD[gp & 3][lane] = d;
                bufC[gp & 3][lane] = c;
            }
        } else if (wv >= 3 && g >= 1) {
            // ---------------- loaders: fold kept rows of group g-1 ----------
            unsigned long long am = aliveLds[g - 1];
            unsigned long long myMask = 0ull;
            {   // round-robin partition of kept bits among waves 3..7
                unsigned long long t = am; int i = 0;
                while (t) {
                    int bb = __builtin_ctzll(t); t &= t - 1;
                    if ((i % 5) == (wv - 3)) myMask |= 1ull << bb;
                    ++i;
                }
            }
            if (myMask) {
                const unsigned long long* bR =
                    R + (((size_t)(g - 1)) << 6) * MASK_WORDS + lane;
                unsigned long long am2 = myMask;
                int i0 = __builtin_ctzll(am2); am2 &= am2 - 1;
                EXTN(i1) EXTN(i2) EXTN(i3) EXTN(i4) EXTN(i5) EXTN(i6) EXTN(i7)
                // straight-line batch: 8 loads, ONE wait, then OR (pads repeat i0)
                unsigned long long t0 = bR[(size_t)i0 * MASK_WORDS];
                unsigned long long t1 = bR[(size_t)i1 * MASK_WORDS];
                unsigned long long t2 = bR[(size_t)i2 * MASK_WORDS];
                unsigned long long t3 = bR[(size_t)i3 * MASK_WORDS];
                unsigned long long t4 = bR[(size_t)i4 * MASK_WORDS];
                unsigned long long t5 = bR[(size_t)i5 * MASK_WORDS];
                unsigned long long t6 = bR[(size_t)i6 * MASK_WORDS];
                unsigned long long t7 = bR[(size_t)i7 * MASK_WORDS];
                unsigned long long acc = ((t0 | t1) | (t2 | t3)) | ((t4 | t5) | (t6 | t7));
                while (am2) {   // >40 kept in one group: rare, serial
                    int j = __builtin_ctzll(am2); am2 &= am2 - 1;
                    acc |= bR[(size_t)j * MASK_WORDS];
                }
                unsigned lo = (unsigned)acc, hi = (unsigned)(acc >> 32);
                if (lo) atomicOr(&remW[lane][0], lo);
                if (hi) atomicOr(&remW[lane][1], hi);
            }
        }
        __syncthreads();
        if (doneLds) break;
    }

    int kc = kcntLds;   // last write barrier-ordered before every exit path
    for (int r = tid; r < POST_NMS; r += 512) {
        float* o = out + ((size_t)b * POST_NMS + r) * 5;
        float4 bx = make_float4(0.f, 0.f, 0.f, 0.f);
        if (r < kc) bx = sortedBoxes[(size_t)b * SORT_N + kept[r]];
        o[0] = (float)b;
        o[1] = bx.x;
        o[2] = bx.y;
        o[3] = bx.z;
        o[4] = bx.w;
    }
}

// ---------------------------------------------------------------------------
extern "C" void kernel_launch(void* const* d_in, const int* in_sizes, int n_in,
                              void* d_out, int out_size, void* d_ws, size_t ws_size,
                              hipStream_t stream) {
    const float* scores  = (const float*)d_in[0];
    const float* deltas  = (const float*)d_in[1];
    const float* im_info = (const float*)d_in[2];
    const float* anchors = (const float*)d_in[3];
    float* out = (float*)d_out;

    char* ws = (char*)d_ws;
    size_t off = 0;
    float4* boxes = (float4*)(ws + off);
    off += (size_t)B_N * N_PROP * sizeof(float4);
    off = (off + 255) & ~(size_t)255;
    unsigned long long* keys = (unsigned long long*)(ws + off);
    off += (size_t)B_N * N_PROP * sizeof(unsigned long long);
    off = (off + 255) & ~(size_t)255;
    float4* sortedBoxes = (float4*)(ws + off);
    off += (size_t)B_N * SORT_N * sizeof(float4);
    off = (off + 255) & ~(size_t)255;
    unsigned long long* colmaj = (unsigned long long*)(ws + off);
    off += (size_t)B_N * MASK_WORDS * SORT_N * sizeof(unsigned long long);
    off = (off + 255) & ~(size_t)255;
    unsigned long long* rowmaj = (unsigned long long*)(ws + off);
    off += (size_t)B_N * SORT_N * MASK_WORDS * sizeof(unsigned long long);
    off = (off + 255) & ~(size_t)255;
    unsigned long long* cand = (unsigned long long*)(ws + off);
    off += (size_t)B_N * CAND_MAX * sizeof(unsigned long long);
    off = (off + 255) & ~(size_t)255;
    unsigned* ghist = (unsigned*)(ws + off);
    size_t zero_off = off;
    off += (size_t)B_N * NBINS * sizeof(unsigned);
    unsigned* cnt = (unsigned*)(ws + off);
    off += (size_t)B_N * sizeof(unsigned);
    size_t zero_bytes = off - zero_off;
    off = (off + 255) & ~(size_t)255;
    int* Tbuf = (int*)(ws + off);
    off += (size_t)B_N * sizeof(int);

    hipMemsetAsync((void*)ghist, 0, zero_bytes, stream);

    int total = B_N * N_PROP;
    decode_kernel<<<(total + 255) / 256, 256, 0, stream>>>(
        scores, deltas, im_info, anchors, boxes, keys, ghist);
    findT_kernel<<<B_N, 64, 0, stream>>>(ghist, Tbuf);
    compact_kernel<<<dim3((N_PROP + 255) / 256, B_N), 256, 0, stream>>>(
        keys, Tbuf, cnt, cand);
    rank_scatter_kernel<<<dim3(CAND_MAX / 64, B_N), 256, 0, stream>>>(
        cand, cnt, boxes, sortedBoxes);
    iou_mask_kernel<<<dim3(64, 64, B_N), 64, 0, stream>>>(sortedBoxes, colmaj, rowmaj);
    nms_scan_kernel<<<B_N, 512, 0, stream>>>(colmaj, rowmaj, sortedBoxes, out);
}

// Round 6
// 274.492 us; speedup vs baseline: 1.1723x; 1.0406x over previous
//
#include <hip/hip_runtime.h>
#include <stdint.h>

#define A_N 9
#define H_N 50
#define W_N 76
#define HW_N (H_N * W_N)      // 3800
#define N_PROP (A_N * HW_N)   // 34200
#define B_N 4
#define PRE_NMS 4000
#define POST_NMS 300
#define NMS_TH 0.7f
#define SORT_N 4096
#define MASK_WORDS 64
#define CAND_MAX 5120
#define NBINS 4096
#define NPAIR 32

// ---------------------------------------------------------------------------
// Kernel A: decode + keys (a-major mapping -> all loads/stores coalesced).
// ---------------------------------------------------------------------------
__global__ void decode_kernel(const float* __restrict__ scores,
                              const float* __restrict__ deltas,
                              const float* __restrict__ im_info,
                              const float* __restrict__ anchors,
                              float4* __restrict__ boxes,
                              unsigned long long* __restrict__ keys,
                              unsigned* __restrict__ ghist) {
#pragma clang fp contract(off)
    int gid = blockIdx.x * blockDim.x + threadIdx.x;
    if (gid >= B_N * N_PROP) return;
    int b = gid / N_PROP;
    int r = gid - b * N_PROP;
    int a = r / HW_N;          // fixed across a wave
    int hw = r - a * HW_N;     // consecutive across lanes
    int hy = hw / W_N;
    int wx = hw - hy * W_N;

    float sx = (float)wx * 16.0f;
    float sy = (float)hy * 16.0f;
    float ax1 = anchors[a * 4 + 0] + sx;
    float ay1 = anchors[a * 4 + 1] + sy;
    float ax2 = anchors[a * 4 + 2] + sx;
    float ay2 = anchors[a * 4 + 3] + sy;
    float aw = ax2 - ax1 + 1.0f;
    float ah = ay2 - ay1 + 1.0f;
    float cx = ax1 + 0.5f * aw;
    float cy = ay1 + 0.5f * ah;

    const float* db = deltas + ((size_t)b * 36 + (size_t)a * 4) * HW_N + hw;
    float d0 = db[0];
    float d1 = db[HW_N];
    float d2 = db[2 * HW_N];
    float d3 = db[3 * HW_N];

    float pcx = d0 * aw + cx;
    float pcy = d1 * ah + cy;
    float pw  = expf(d2) * aw;
    float ph  = expf(d3) * ah;

    float x1 = pcx - 0.5f * pw;
    float y1 = pcy - 0.5f * ph;
    float x2 = pcx + 0.5f * pw;
    float y2 = pcy + 0.5f * ph;

    float xhi = im_info[b * 3 + 1] - 1.0f;
    float yhi = im_info[b * 3 + 0] - 1.0f;
    x1 = fminf(fmaxf(x1, 0.0f), xhi);
    y1 = fminf(fmaxf(y1, 0.0f), yhi);
    x2 = fminf(fmaxf(x2, 0.0f), xhi);
    y2 = fminf(fmaxf(y2, 0.0f), yhi);

    boxes[gid] = make_float4(x1, y1, x2, y2);  // a-major layout

    float s = scores[((size_t)b * A_N + a) * HW_N + hw];
    unsigned f = __float_as_uint(s);
    unsigned sk = f ^ ((f & 0x80000000u) ? 0xFFFFFFFFu : 0x80000000u);
    unsigned n_ref = (unsigned)(hw * A_N + a);
    unsigned long long key = ((unsigned long long)sk << 32) | (unsigned)(~n_ref);
    keys[gid] = key;
    atomicAdd(&ghist[b * NBINS + (unsigned)(key >> 52)], 1u);
}

// ---------------------------------------------------------------------------
// Kernel B: threshold bucket T via two wave-level suffix scans.
// ---------------------------------------------------------------------------
__global__ __launch_bounds__(64) void findT_kernel(const unsigned* __restrict__ ghist,
                                                   int* __restrict__ Tout) {
    __shared__ unsigned h[NBINS];
    int b = blockIdx.x;
    int lane = threadIdx.x;  // 64
    for (int i = lane; i < NBINS; i += 64) h[i] = ghist[b * NBINS + i];
    __syncthreads();
    unsigned gsum = 0;
    for (int j = 0; j < 64; ++j) gsum += h[lane * 64 + j];
    unsigned s = gsum;
    for (int d = 1; d < 64; d <<= 1) {
        unsigned t = (unsigned)__shfl_down((int)s, d);
        if (lane + d < 64) s += t;
    }
    unsigned long long bal = __ballot(s >= PRE_NMS);
    int gstar = 63 - __builtin_clzll(bal);
    unsigned after = (gstar < 63) ? (unsigned)__builtin_amdgcn_readlane((int)s, gstar + 1) : 0u;
    unsigned R = PRE_NMS - after;
    unsigned s2 = h[gstar * 64 + lane];
    for (int d = 1; d < 64; d <<= 1) {
        unsigned t = (unsigned)__shfl_down((int)s2, d);
        if (lane + d < 64) s2 += t;
    }
    unsigned long long bal2 = __ballot(s2 >= R);
    int j = 63 - __builtin_clzll(bal2);
    if (lane == 0) Tout[b] = gstar * 64 + j;
}

// ---------------------------------------------------------------------------
// Kernel C: compact candidates; wave-aggregated atomic.
// ---------------------------------------------------------------------------
__global__ void compact_kernel(const unsigned long long* __restrict__ keys,
                               const int* __restrict__ T,
                               unsigned* __restrict__ cnt,
                               unsigned long long* __restrict__ cand) {
    int b = blockIdx.y;
    int n = blockIdx.x * 256 + threadIdx.x;
    bool pred = false;
    unsigned long long k = 0ull;
    if (n < N_PROP) {
        k = keys[(size_t)b * N_PROP + n];
        pred = ((int)(unsigned)(k >> 52) >= T[b]);
    }
    unsigned long long m = __ballot(pred);
    if (m) {
        int lane = threadIdx.x & 63;
        int lead = __ffsll((unsigned long long)m) - 1;
        unsigned base = 0;
        if (lane == lead) base = atomicAdd(&cnt[b], (unsigned)__popcll(m));
        base = __shfl((int)base, lead);
        if (pred) {
            unsigned pos = base + (unsigned)__popcll(m & ((1ull << lane) - 1ull));
            if (pos < CAND_MAX) cand[(size_t)b * CAND_MAX + pos] = k;
        }
    }
}

// ---------------------------------------------------------------------------
// Kernel D: exact rank by pairwise count, 4-way j-split per candidate.
// ---------------------------------------------------------------------------
__global__ __launch_bounds__(256) void rank_scatter_kernel(
    const unsigned long long* __restrict__ cand,
    const unsigned* __restrict__ cnt,
    const float4* __restrict__ boxes,
    float4* __restrict__ sortedBoxes) {
    __shared__ unsigned long long sk[256];
    int b = blockIdx.y;
    int tid = threadIdx.x;
    int ci = blockIdx.x * 64 + (tid >> 2);
    int q = tid & 3;
    int mc = (int)min(cnt[b], (unsigned)CAND_MAX);
    unsigned long long my = (ci < mc) ? cand[(size_t)b * CAND_MAX + ci] : 0ull;
    int rank = 0;
    int nt = (mc + 255) >> 8;
    for (int t = 0; t < nt; ++t) {
        int j = t * 256 + tid;
        sk[tid] = (j < mc) ? cand[(size_t)b * CAND_MAX + j] : 0ull;
        __syncthreads();
#pragma unroll 16
        for (int c = 0; c < 64; ++c) {
            int cc = q * 64 + ((c + q * 17) & 63);  // stagger: avoid 4-way bank conflict
            rank += (sk[cc] > my) ? 1 : 0;
        }
        __syncthreads();
    }
    rank += __shfl_xor(rank, 1);
    rank += __shfl_xor(rank, 2);
    if (q == 0 && ci < mc && rank < PRE_NMS) {
        unsigned n_ref = ~(unsigned)(my & 0xFFFFFFFFull);
        unsigned a = n_ref % A_N;
        unsigned hw = n_ref / A_N;
        sortedBoxes[(size_t)b * SORT_N + rank] =
            boxes[(size_t)b * N_PROP + a * HW_N + hw];
    }
    if (q == 1) {
        int pi = blockIdx.x * 64 + (tid >> 2);
        if (pi >= PRE_NMS && pi < SORT_N)
            sortedBoxes[(size_t)b * SORT_N + pi] = make_float4(0.f, 0.f, 0.f, 0.f);
    }
}

// ---------------------------------------------------------------------------
// Kernel E: suppression bitmask, upper-triangle-only grid.
// 2080 tiles per batch (rc<=cc), 4 waves/block, one tile per wave — was
// 16384 blocks of 64 threads with half returning immediately (dispatch
// overhead probe for the constant ~217us non-scan residual).
//   colmaj[cc*SORT_N + r]  (coalesced store; prefetch waves' tile reads)
//   rowmaj[r*64 + cc]      (scatter store; loader waves' row reads COALESCED)
// ---------------------------------------------------------------------------
__global__ __launch_bounds__(256) void iou_mask_kernel(
    const float4* __restrict__ sortedBoxes,
    unsigned long long* __restrict__ colmaj,
    unsigned long long* __restrict__ rowmaj) {
#pragma clang fp contract(off)
    int b = blockIdx.y;
    int wv = threadIdx.x >> 6;
    int t = threadIdx.x & 63;
    int k = blockIdx.x * 4 + wv;          // 0..2079, upper-tri linear index
    int rc = 0;
    while (k >= 64 - rc) { k -= 64 - rc; ++rc; }
    int cc = rc + k;

    __shared__ float4 colb[4][64];
    colb[wv][t] = sortedBoxes[(size_t)b * SORT_N + cc * 64 + t];
    __syncthreads();

    int r = rc * 64 + t;
    float4 rb = sortedBoxes[(size_t)b * SORT_N + r];
    float rarea = (rb.z - rb.x) * (rb.w - rb.y);
    unsigned long long word = 0ull;
    for (int c = 0; c < 64; ++c) {
        int j = cc * 64 + c;
        float4 cb = colb[wv][c];
        float carea = (cb.z - cb.x) * (cb.w - cb.y);
        float ltx = fmaxf(rb.x, cb.x);
        float lty = fmaxf(rb.y, cb.y);
        float rbx = fminf(rb.z, cb.z);
        float rby = fminf(rb.w, cb.w);
        float iw = fmaxf(rbx - ltx, 0.0f);
        float ih = fmaxf(rby - lty, 0.0f);
        float inter = iw * ih;
        float iou = inter / (rarea + carea - inter + 1e-9f);
        if (iou > NMS_TH && j > r) word |= (1ull << c);
    }
    colmaj[((size_t)b * MASK_WORDS + cc) * SORT_N + r] = word;   // coalesced
    rowmaj[((size_t)b * SORT_N + r) * MASK_WORDS + cc] = word;   // scatter
}

// ---------------------------------------------------------------------------
// Kernel F: MULTI-WAVE greedy scan, PAIR-PROCESSED (2 groups per barrier
// iteration -> 32 iterations). r5 showed the per-iteration floor is the
// loader waves' load latency + fixed overhead (decider LDS-ring gave 0);
// halving the iteration count halves that bill.
//   wv0   = decider   : chains groups A=2q,B=2q+1 from the LDS tile ring;
//                       exact within-pair carry (A->B) and next-pair carries
//                       (words 2q+2, 2q+3) from this pair's kept bits.
//   wv1-2 = prefetch  : wave 1+(q&1) stages pair q+2's 7 tiles
//                       {dA, A->B, A->+2, A->+3, dB, B->+1, B->+2}
//                       into a 4-slot ring (reuse distance 4 iterations).
//   wv3-7 = loaders   : fold kept rows of PAIR q-1 (both groups) into remW
//                       via LDS atomicOr; 8-row named-register batch per
//                       wave (rowmaj, coalesced 512B/row), serial overflow.
// Ordering: decide(q) sees folds of pairs <= q-2 via remW, pair q-1 exactly
// via carries. Loader writes to words 2q/2q+1 during iter q are a subset of
// carA/carB (idempotent OR, benign race). Lower-tri poison words fold only
// into remW words already consumed (barrier-ordered) — unchanged from r4.
// ---------------------------------------------------------------------------
__device__ inline unsigned long long rl64(unsigned long long v, int src) {
    unsigned lo = (unsigned)__builtin_amdgcn_readlane((int)(unsigned)(v & 0xFFFFFFFFull), src);
    unsigned hi = (unsigned)__builtin_amdgcn_readlane((int)(unsigned)(v >> 32), src);
    return ((unsigned long long)hi << 32) | lo;
}

#define NEXTROW(rk)                                                            \
    int rk;                                                                    \
    {                                                                          \
        if (mA) { int bb_ = __builtin_ctzll(mA); mA &= mA - 1; rk = baseA + bb_; } \
        else if (mB) { int bb_ = __builtin_ctzll(mB); mB &= mB - 1; rk = baseB + bb_; } \
        else rk = rpad;                                                        \
    }

#define STAGE_PAIR(QP)                                                         \
    do {                                                                       \
        int A_ = 2 * (QP), B_ = 2 * (QP) + 1, slot_ = (QP) & 3;                \
        size_t rbA_ = (size_t)A_ << 6, rbB_ = (size_t)B_ << 6;                 \
        unsigned long long s0 = C[(size_t)A_ * SORT_N + rbA_ + lane];          \
        unsigned long long s1 = C[(size_t)B_ * SORT_N + rbA_ + lane];          \
        unsigned long long s2 = (A_ + 2 < 64) ? C[(size_t)(A_ + 2) * SORT_N + rbA_ + lane] : 0ull; \
        unsigned long long s3 = (A_ + 3 < 64) ? C[(size_t)(A_ + 3) * SORT_N + rbA_ + lane] : 0ull; \
        unsigned long long s4 = C[(size_t)B_ * SORT_N + rbB_ + lane];          \
        unsigned long long s5 = (B_ + 1 < 64) ? C[(size_t)(B_ + 1) * SORT_N + rbB_ + lane] : 0ull; \
        unsigned long long s6 = (B_ + 2 < 64) ? C[(size_t)(B_ + 2) * SORT_N + rbB_ + lane] : 0ull; \
        bufT[slot_][0][lane] = s0; bufT[slot_][1][lane] = s1;                  \
        bufT[slot_][2][lane] = s2; bufT[slot_][3][lane] = s3;                  \
        bufT[slot_][4][lane] = s4; bufT[slot_][5][lane] = s5;                  \
        bufT[slot_][6][lane] = s6;                                             \
    } while (0)

__global__ __launch_bounds__(512, 1) void nms_scan_kernel(
    const unsigned long long* __restrict__ colmaj,
    const unsigned long long* __restrict__ rowmaj,
    const float4* __restrict__ sortedBoxes,
    float* __restrict__ out) {
    int b = blockIdx.x;
    int tid = threadIdx.x;
    int lane = tid & 63;
    int wv = tid >> 6;                 // 0=decider, 1-2=prefetch, 3-7=loaders
    const unsigned long long* C = colmaj + (size_t)b * MASK_WORDS * SORT_N;
    const unsigned long long* R = rowmaj + (size_t)b * SORT_N * MASK_WORDS;

    __shared__ int kept[POST_NMS];
    __shared__ unsigned remW[MASK_WORDS][2];            // [word][lo,hi]
    __shared__ unsigned long long aliveLds[MASK_WORDS];
    __shared__ unsigned long long bufT[4][7][64];       // tile ring (pair&3)
    __shared__ int doneLds;
    __shared__ int kcntLds;

    if (tid < MASK_WORDS) { remW[tid][0] = 0u; remW[tid][1] = 0u; aliveLds[tid] = 0ull; }
    if (tid == 0) { doneLds = 0; kcntLds = 0; }
    // prologue: stage pairs 0 and 1 into ring slots 0,1
    if (wv == 1) STAGE_PAIR(0);
    if (wv == 2) STAGE_PAIR(1);
    __syncthreads();

    unsigned long long carA = 0ull, carB = 0ull;  // decider: exact carries from pair q-1
    int kcnt = 0;

    for (int q = 0; q < NPAIR; ++q) {
        if (wv == 0) {
            // ---------------- decider: groups A=2q, B=2q+1 ----------------
            int A = 2 * q, Bg = 2 * q + 1, slot = q & 3;
            unsigned long long dA  = bufT[slot][0][lane];
            unsigned long long c1A = bufT[slot][1][lane];
            unsigned long long c2A = bufT[slot][2][lane];
            unsigned long long c3A = bufT[slot][3][lane];
            unsigned long long dB  = bufT[slot][4][lane];
            unsigned long long c1B = bufT[slot][5][lane];
            unsigned long long c2B = bufT[slot][6][lane];
            unsigned long long remA =
                ((unsigned long long)remW[A][1] << 32) | (unsigned long long)remW[A][0];
            unsigned long long remB =
                ((unsigned long long)remW[Bg][1] << 32) | (unsigned long long)remW[Bg][0];
            bool hit = false;
            // chain group A
            unsigned long long pend = ~(remA | carA);
            unsigned long long aliveA = 0ull, aliveB = 0ull;
            while (pend) {
                int bit = __builtin_ctzll(pend);
                if (lane == 0) kept[kcnt] = (A << 6) + bit;
                ++kcnt;
                aliveA |= 1ull << bit;
                if (kcnt == POST_NMS) { hit = true; break; }
                unsigned long long d = rl64(dA, bit);
                pend &= ~(d | (1ull << bit));
            }
            unsigned long long nA1 = 0ull, nA2 = 0ull, nA3 = 0ull;
            if (!hit) {
                unsigned long long am = aliveA;
                while (am) {
                    int i = __builtin_ctzll(am); am &= am - 1;
                    nA1 |= rl64(c1A, i); nA2 |= rl64(c2A, i); nA3 |= rl64(c3A, i);
                }
                // chain group B (within-pair suppression nA1 is exact)
                pend = ~(remB | carB | nA1);
                while (pend) {
                    int bit = __builtin_ctzll(pend);
                    if (lane == 0) kept[kcnt] = (Bg << 6) + bit;
                    ++kcnt;
                    aliveB |= 1ull << bit;
                    if (kcnt == POST_NMS) { hit = true; break; }
                    unsigned long long d = rl64(dB, bit);
                    pend &= ~(d | (1ull << bit));
                }
            }
            unsigned long long nB1 = 0ull, nB2 = 0ull;
            if (!hit) {
                unsigned long long am = aliveB;
                while (am) {
                    int i = __builtin_ctzll(am); am &= am - 1;
                    nB1 |= rl64(c1B, i); nB2 |= rl64(c2B, i);
                }
            }
            carA = nA2 | nB1;   // next pair word 2q+2
            carB = nA3 | nB2;   // next pair word 2q+3
            if (lane == 0) {
                aliveLds[A]  = aliveA;
                aliveLds[Bg] = aliveB;
                kcntLds = kcnt;
                if (hit) doneLds = 1;
            }
        } else if (wv == 1 + (q & 1)) {
            // ---------------- prefetch: stage pair q+2 ----------------
            int qp = q + 2;
            if (qp < NPAIR) STAGE_PAIR(qp);
        } else if (wv >= 3 && q >= 1) {
            // ---------------- loaders: fold kept rows of pair q-1 ----------
            int gA = 2 * q - 2, gB = 2 * q - 1;
            unsigned long long amA = aliveLds[gA], amB = aliveLds[gB];
            unsigned long long myA = 0ull, myB = 0ull;
            {   // round-robin partition (concatenated index) among waves 3..7
                unsigned long long t1 = amA; int i = 0;
                while (t1) {
                    int bb = __builtin_ctzll(t1); t1 &= t1 - 1;
                    if ((i % 5) == (wv - 3)) myA |= 1ull << bb;
                    ++i;
                }
                unsigned long long t2 = amB;
                while (t2) {
                    int bb = __builtin_ctzll(t2); t2 &= t2 - 1;
                    if ((i % 5) == (wv - 3)) myB |= 1ull << bb;
                    ++i;
                }
            }
            if (myA | myB) {
                int baseA = gA << 6, baseB = gB << 6;
                unsigned long long mA = myA, mB = myB;
                int rpad = myA ? (baseA + __builtin_ctzll(myA))
                               : (baseB + __builtin_ctzll(myB));
                NEXTROW(r0) NEXTROW(r1) NEXTROW(r2) NEXTROW(r3)
                NEXTROW(r4) NEXTROW(r5) NEXTROW(r6) NEXTROW(r7)
                const unsigned long long* Rb = R + lane;
                unsigned long long t0 = Rb[(size_t)r0 * MASK_WORDS];
                unsigned long long t1 = Rb[(size_t)r1 * MASK_WORDS];
                unsigned long long t2 = Rb[(size_t)r2 * MASK_WORDS];
                unsigned long long t3 = Rb[(size_t)r3 * MASK_WORDS];
                unsigned long long t4 = Rb[(size_t)r4 * MASK_WORDS];
                unsigned long long t5 = Rb[(size_t)r5 * MASK_WORDS];
                unsigned long long t6 = Rb[(size_t)r6 * MASK_WORDS];
                unsigned long long t7 = Rb[(size_t)r7 * MASK_WORDS];
                unsigned long long acc = ((t0 | t1) | (t2 | t3)) | ((t4 | t5) | (t6 | t7));
                while (mA) {   // >8 rows for this wave: rare, serial
                    int bb = __builtin_ctzll(mA); mA &= mA - 1;
                    acc |= Rb[(size_t)(baseA + bb) * MASK_WORDS];
                }
                while (mB) {
                    int bb = __builtin_ctzll(mB); mB &= mB - 1;
                    acc |= Rb[(size_t)(baseB + bb) * MASK_WORDS];
                }
                unsigned lo = (unsigned)acc, hi = (unsigned)(acc >> 32);
                if (lo) atomicOr(&remW[lane][0], lo);
                if (hi) atomicOr(&remW[lane][1], hi);
            }
        }
        __syncthreads();
        if (doneLds) break;
    }

    int kc = kcntLds;   // last write barrier-ordered before every exit path
    for (int r = tid; r < POST_NMS; r += 512) {
        float* o = out + ((size_t)b * POST_NMS + r) * 5;
        float4 bx = make_float4(0.f, 0.f, 0.f, 0.f);
        if (r < kc) bx = sortedBoxes[(size_t)b * SORT_N + kept[r]];
        o[0] = (float)b;
        o[1] = bx.x;
        o[2] = bx.y;
        o[3] = bx.z;
        o[4] = bx.w;
    }
}

// ---------------------------------------------------------------------------
extern "C" void kernel_launch(void* const* d_in, const int* in_sizes, int n_in,
                              void* d_out, int out_size, void* d_ws, size_t ws_size,
                              hipStream_t stream) {
    const float* scores  = (const float*)d_in[0];
    const float* deltas  = (const float*)d_in[1];
    const float* im_info = (const float*)d_in[2];
    const float* anchors = (const float*)d_in[3];
    float* out = (float*)d_out;

    char* ws = (char*)d_ws;
    size_t off = 0;
    float4* boxes = (float4*)(ws + off);
    off += (size_t)B_N * N_PROP * sizeof(float4);
    off = (off + 255) & ~(size_t)255;
    unsigned long long* keys = (unsigned long long*)(ws + off);
    off += (size_t)B_N * N_PROP * sizeof(unsigned long long);
    off = (off + 255) & ~(size_t)255;
    float4* sortedBoxes = (float4*)(ws + off);
    off += (size_t)B_N * SORT_N * sizeof(float4);
    off = (off + 255) & ~(size_t)255;
    unsigned long long* colmaj = (unsigned long long*)(ws + off);
    off += (size_t)B_N * MASK_WORDS * SORT_N * sizeof(unsigned long long);
    off = (off + 255) & ~(size_t)255;
    unsigned long long* rowmaj = (unsigned long long*)(ws + off);
    off += (size_t)B_N * SORT_N * MASK_WORDS * sizeof(unsigned long long);
    off = (off + 255) & ~(size_t)255;
    unsigned long long* cand = (unsigned long long*)(ws + off);
    off += (size_t)B_N * CAND_MAX * sizeof(unsigned long long);
    off = (off + 255) & ~(size_t)255;
    unsigned* ghist = (unsigned*)(ws + off);
    size_t zero_off = off;
    off += (size_t)B_N * NBINS * sizeof(unsigned);
    unsigned* cnt = (unsigned*)(ws + off);
    off += (size_t)B_N * sizeof(unsigned);
    size_t zero_bytes = off - zero_off;
    off = (off + 255) & ~(size_t)255;
    int* Tbuf = (int*)(ws + off);
    off += (size_t)B_N * sizeof(int);

    hipMemsetAsync((void*)ghist, 0, zero_bytes, stream);

    int total = B_N * N_PROP;
    decode_kernel<<<(total + 255) / 256, 256, 0, stream>>>(
        scores, deltas, im_info, anchors, boxes, keys, ghist);
    findT_kernel<<<B_N, 64, 0, stream>>>(ghist, Tbuf);
    compact_kernel<<<dim3((N_PROP + 255) / 256, B_N), 256, 0, stream>>>(
        keys, Tbuf, cnt, cand);
    rank_scatter_kernel<<<dim3(CAND_MAX / 64, B_N), 256, 0, stream>>>(
        cand, cnt, boxes, sortedBoxes);
    iou_mask_kernel<<<dim3(520, B_N), 256, 0, stream>>>(sortedBoxes, colmaj, rowmaj);
    nms_scan_kernel<<<B_N, 512, 0, stream>>>(colmaj, rowmaj, sortedBoxes, out);
}

// Round 7
// 262.059 us; speedup vs baseline: 1.2279x; 1.0474x over previous
//
#include <hip/hip_runtime.h>
#include <stdint.h>

#define A_N 9
#define H_N 50
#define W_N 76
#define HW_N (H_N * W_N)      // 3800
#define N_PROP (A_N * HW_N)   // 34200
#define B_N 4
#define PRE_NMS 4000
#define POST_NMS 300
#define NMS_TH 0.7f
#define SORT_N 4096
#define MASK_WORDS 64
#define CAND_MAX 5120
#define NBINS 4096
#define NPAIR 32
#define NLW 5                 // loader waves

// ---------------------------------------------------------------------------
// Kernel A: decode + keys (a-major mapping -> all loads/stores coalesced).
// ---------------------------------------------------------------------------
__global__ void decode_kernel(const float* __restrict__ scores,
                              const float* __restrict__ deltas,
                              const float* __restrict__ im_info,
                              const float* __restrict__ anchors,
                              float4* __restrict__ boxes,
                              unsigned long long* __restrict__ keys,
                              unsigned* __restrict__ ghist) {
#pragma clang fp contract(off)
    int gid = blockIdx.x * blockDim.x + threadIdx.x;
    if (gid >= B_N * N_PROP) return;
    int b = gid / N_PROP;
    int r = gid - b * N_PROP;
    int a = r / HW_N;          // fixed across a wave
    int hw = r - a * HW_N;     // consecutive across lanes
    int hy = hw / W_N;
    int wx = hw - hy * W_N;

    float sx = (float)wx * 16.0f;
    float sy = (float)hy * 16.0f;
    float ax1 = anchors[a * 4 + 0] + sx;
    float ay1 = anchors[a * 4 + 1] + sy;
    float ax2 = anchors[a * 4 + 2] + sx;
    float ay2 = anchors[a * 4 + 3] + sy;
    float aw = ax2 - ax1 + 1.0f;
    float ah = ay2 - ay1 + 1.0f;
    float cx = ax1 + 0.5f * aw;
    float cy = ay1 + 0.5f * ah;

    const float* db = deltas + ((size_t)b * 36 + (size_t)a * 4) * HW_N + hw;
    float d0 = db[0];
    float d1 = db[HW_N];
    float d2 = db[2 * HW_N];
    float d3 = db[3 * HW_N];

    float pcx = d0 * aw + cx;
    float pcy = d1 * ah + cy;
    float pw  = expf(d2) * aw;
    float ph  = expf(d3) * ah;

    float x1 = pcx - 0.5f * pw;
    float y1 = pcy - 0.5f * ph;
    float x2 = pcx + 0.5f * pw;
    float y2 = pcy + 0.5f * ph;

    float xhi = im_info[b * 3 + 1] - 1.0f;
    float yhi = im_info[b * 3 + 0] - 1.0f;
    x1 = fminf(fmaxf(x1, 0.0f), xhi);
    y1 = fminf(fmaxf(y1, 0.0f), yhi);
    x2 = fminf(fmaxf(x2, 0.0f), xhi);
    y2 = fminf(fmaxf(y2, 0.0f), yhi);

    boxes[gid] = make_float4(x1, y1, x2, y2);  // a-major layout

    float s = scores[((size_t)b * A_N + a) * HW_N + hw];
    unsigned f = __float_as_uint(s);
    unsigned sk = f ^ ((f & 0x80000000u) ? 0xFFFFFFFFu : 0x80000000u);
    unsigned n_ref = (unsigned)(hw * A_N + a);
    unsigned long long key = ((unsigned long long)sk << 32) | (unsigned)(~n_ref);
    keys[gid] = key;
    atomicAdd(&ghist[b * NBINS + (unsigned)(key >> 52)], 1u);
}

// ---------------------------------------------------------------------------
// Kernel B: threshold bucket T via two wave-level suffix scans.
// ---------------------------------------------------------------------------
__global__ __launch_bounds__(64) void findT_kernel(const unsigned* __restrict__ ghist,
                                                   int* __restrict__ Tout) {
    __shared__ unsigned h[NBINS];
    int b = blockIdx.x;
    int lane = threadIdx.x;  // 64
    for (int i = lane; i < NBINS; i += 64) h[i] = ghist[b * NBINS + i];
    __syncthreads();
    unsigned gsum = 0;
    for (int j = 0; j < 64; ++j) gsum += h[lane * 64 + j];
    unsigned s = gsum;
    for (int d = 1; d < 64; d <<= 1) {
        unsigned t = (unsigned)__shfl_down((int)s, d);
        if (lane + d < 64) s += t;
    }
    unsigned long long bal = __ballot(s >= PRE_NMS);
    int gstar = 63 - __builtin_clzll(bal);
    unsigned after = (gstar < 63) ? (unsigned)__builtin_amdgcn_readlane((int)s, gstar + 1) : 0u;
    unsigned R = PRE_NMS - after;
    unsigned s2 = h[gstar * 64 + lane];
    for (int d = 1; d < 64; d <<= 1) {
        unsigned t = (unsigned)__shfl_down((int)s2, d);
        if (lane + d < 64) s2 += t;
    }
    unsigned long long bal2 = __ballot(s2 >= R);
    int j = 63 - __builtin_clzll(bal2);
    if (lane == 0) Tout[b] = gstar * 64 + j;
}

// ---------------------------------------------------------------------------
// Kernel C: compact candidates; wave-aggregated atomic.
// ---------------------------------------------------------------------------
__global__ void compact_kernel(const unsigned long long* __restrict__ keys,
                               const int* __restrict__ T,
                               unsigned* __restrict__ cnt,
                               unsigned long long* __restrict__ cand) {
    int b = blockIdx.y;
    int n = blockIdx.x * 256 + threadIdx.x;
    bool pred = false;
    unsigned long long k = 0ull;
    if (n < N_PROP) {
        k = keys[(size_t)b * N_PROP + n];
        pred = ((int)(unsigned)(k >> 52) >= T[b]);
    }
    unsigned long long m = __ballot(pred);
    if (m) {
        int lane = threadIdx.x & 63;
        int lead = __ffsll((unsigned long long)m) - 1;
        unsigned base = 0;
        if (lane == lead) base = atomicAdd(&cnt[b], (unsigned)__popcll(m));
        base = __shfl((int)base, lead);
        if (pred) {
            unsigned pos = base + (unsigned)__popcll(m & ((1ull << lane) - 1ull));
            if (pos < CAND_MAX) cand[(size_t)b * CAND_MAX + pos] = k;
        }
    }
}

// ---------------------------------------------------------------------------
// Kernel D: exact rank by pairwise count, 4-way j-split per candidate.
// ---------------------------------------------------------------------------
__global__ __launch_bounds__(256) void rank_scatter_kernel(
    const unsigned long long* __restrict__ cand,
    const unsigned* __restrict__ cnt,
    const float4* __restrict__ boxes,
    float4* __restrict__ sortedBoxes) {
    __shared__ unsigned long long sk[256];
    int b = blockIdx.y;
    int tid = threadIdx.x;
    int ci = blockIdx.x * 64 + (tid >> 2);
    int q = tid & 3;
    int mc = (int)min(cnt[b], (unsigned)CAND_MAX);
    unsigned long long my = (ci < mc) ? cand[(size_t)b * CAND_MAX + ci] : 0ull;
    int rank = 0;
    int nt = (mc + 255) >> 8;
    for (int t = 0; t < nt; ++t) {
        int j = t * 256 + tid;
        sk[tid] = (j < mc) ? cand[(size_t)b * CAND_MAX + j] : 0ull;
        __syncthreads();
#pragma unroll 16
        for (int c = 0; c < 64; ++c) {
            int cc = q * 64 + ((c + q * 17) & 63);  // stagger: avoid 4-way bank conflict
            rank += (sk[cc] > my) ? 1 : 0;
        }
        __syncthreads();
    }
    rank += __shfl_xor(rank, 1);
    rank += __shfl_xor(rank, 2);
    if (q == 0 && ci < mc && rank < PRE_NMS) {
        unsigned n_ref = ~(unsigned)(my & 0xFFFFFFFFull);
        unsigned a = n_ref % A_N;
        unsigned hw = n_ref / A_N;
        sortedBoxes[(size_t)b * SORT_N + rank] =
            boxes[(size_t)b * N_PROP + a * HW_N + hw];
    }
    if (q == 1) {
        int pi = blockIdx.x * 64 + (tid >> 2);
        if (pi >= PRE_NMS && pi < SORT_N)
            sortedBoxes[(size_t)b * SORT_N + pi] = make_float4(0.f, 0.f, 0.f, 0.f);
    }
}

// ---------------------------------------------------------------------------
// Kernel E: suppression bitmask, upper-triangle-only grid (2080 tiles/batch,
// 4 waves/block).
//   colmaj[cc*SORT_N + r]  (coalesced store; prefetch wave's tile reads)
//   rowmaj[r*64 + cc]      (scatter store; loader waves' row reads COALESCED)
// ---------------------------------------------------------------------------
__global__ __launch_bounds__(256) void iou_mask_kernel(
    const float4* __restrict__ sortedBoxes,
    unsigned long long* __restrict__ colmaj,
    unsigned long long* __restrict__ rowmaj) {
#pragma clang fp contract(off)
    int b = blockIdx.y;
    int wv = threadIdx.x >> 6;
    int t = threadIdx.x & 63;
    int k = blockIdx.x * 4 + wv;          // 0..2079, upper-tri linear index
    int rc = 0;
    while (k >= 64 - rc) { k -= 64 - rc; ++rc; }
    int cc = rc + k;

    __shared__ float4 colb[4][64];
    colb[wv][t] = sortedBoxes[(size_t)b * SORT_N + cc * 64 + t];
    __syncthreads();

    int r = rc * 64 + t;
    float4 rb = sortedBoxes[(size_t)b * SORT_N + r];
    float rarea = (rb.z - rb.x) * (rb.w - rb.y);
    unsigned long long word = 0ull;
    for (int c = 0; c < 64; ++c) {
        int j = cc * 64 + c;
        float4 cb = colb[wv][c];
        float carea = (cb.z - cb.x) * (cb.w - cb.y);
        float ltx = fmaxf(rb.x, cb.x);
        float lty = fmaxf(rb.y, cb.y);
        float rbx = fminf(rb.z, cb.z);
        float rby = fminf(rb.w, cb.w);
        float iw = fmaxf(rbx - ltx, 0.0f);
        float ih = fmaxf(rby - lty, 0.0f);
        float inter = iw * ih;
        float iou = inter / (rarea + carea - inter + 1e-9f);
        if (iou > NMS_TH && j > r) word |= (1ull << c);
    }
    colmaj[((size_t)b * MASK_WORDS + cc) * SORT_N + r] = word;   // coalesced
    rowmaj[((size_t)b * SORT_N + r) * MASK_WORDS + cc] = word;   // scatter
}

// ---------------------------------------------------------------------------
// Kernel F: MULTI-WAVE greedy scan, RAW-BARRIER PIPELINED.
// r4-r6 evidence: __syncthreads() drains vmcnt(0) -> every iteration eats a
// full exposed global-load round trip; structure changes (iteration count,
// decider LDS ring) gave ~0. Fix = T3/T4: raw s_barrier (no vmcnt drain) +
// inline-asm GLOADs issued one iteration ahead + counted wait (vmcnt(0) at
// fold = free, loads had a whole iteration in flight). Roles:
//   wv0   decider: chain pair q; carries via 64-lane shfl-OR reductions.
//   wv1   prefetch (pipelined): GLOAD pair q+2's 11 tiles at iter q;
//         vmcnt(0)+ds_write at q+1; decider reads at q+2.
//   wv2   helper: pair p's distance-2 carries (words 2p+4/5) at iter p+1,
//         read by decider at p+2 (closes the deferred-fold gap).
//   wv3-7 loaders (pipelined): issue 8 GLOADs for pair q-1's kept rows at
//         iter q; fold + LDS atomicOr at q+1 (visible q+2). 8 u64 asm
//         outputs/wave across one barrier (~16 VGPR, no spill risk).
// Coverage at decider(q): remW (pairs <= q-3) + helper (pair q-2) + own
// carries (pair q-1, exact). Races: loaders' writes to words 2q/2q+1 are
// subsets of carries/helper (idempotent OR). Lower-tri poison folds only
// into words already consumed (barrier-ordered) — unchanged from r4.
// ---------------------------------------------------------------------------
__device__ __forceinline__ unsigned long long rl64(unsigned long long v, int src) {
    unsigned lo = (unsigned)__builtin_amdgcn_readlane((int)(unsigned)(v & 0xFFFFFFFFull), src);
    unsigned hi = (unsigned)__builtin_amdgcn_readlane((int)(unsigned)(v >> 32), src);
    return ((unsigned long long)hi << 32) | lo;
}

__device__ __forceinline__ unsigned long long redor64(unsigned long long alive,
                                                      unsigned long long v, int lane) {
    unsigned long long x = ((alive >> lane) & 1ull) ? v : 0ull;
    x |= __shfl_xor(x, 1);
    x |= __shfl_xor(x, 2);
    x |= __shfl_xor(x, 4);
    x |= __shfl_xor(x, 8);
    x |= __shfl_xor(x, 16);
    x |= __shfl_xor(x, 32);
    return x;
}

__device__ __forceinline__ void block_sync() {
    asm volatile("s_waitcnt lgkmcnt(0)" ::: "memory");   // LDS visibility, NO vmcnt drain
    __builtin_amdgcn_s_barrier();
    asm volatile("" ::: "memory");                       // compiler fence after barrier
}

#define GLOAD(dst, addr) \
    asm volatile("global_load_dwordx2 %0, %1, off" : "=v"(dst) : "v"(addr))
#define WAITV0 asm volatile("s_waitcnt vmcnt(0)" ::: "memory")
#define SCHED0 __builtin_amdgcn_sched_barrier(0)

// tile t of pair P: t<6 -> col 2P+t over rows of group 2P; t>=6 -> col
// 2P+1+(t-6) over rows of group 2P+1. Clamp col for address, zero on write.
#define TILE_COL(P, t) ((t) < 6 ? 2 * (P) + (t) : 2 * (P) + 1 + ((t) - 6))
#define TILE_RB(P, t)  ((size_t)((t) < 6 ? 2 * (P) : 2 * (P) + 1) << 6)
#define TILE_ADDR(P, t) \
    (C + (size_t)(TILE_COL(P, t) < 64 ? TILE_COL(P, t) : 63) * SORT_N + TILE_RB(P, t) + lane)

#define ISSUE_PAIR(P)                                                          \
    do {                                                                       \
        pf_vmask = 0u;                                                         \
        GLOAD(pf0,  TILE_ADDR(P, 0));  if (TILE_COL(P, 0)  < 64) pf_vmask |= 1u << 0;  \
        GLOAD(pf1,  TILE_ADDR(P, 1));  if (TILE_COL(P, 1)  < 64) pf_vmask |= 1u << 1;  \
        GLOAD(pf2,  TILE_ADDR(P, 2));  if (TILE_COL(P, 2)  < 64) pf_vmask |= 1u << 2;  \
        GLOAD(pf3,  TILE_ADDR(P, 3));  if (TILE_COL(P, 3)  < 64) pf_vmask |= 1u << 3;  \
        GLOAD(pf4,  TILE_ADDR(P, 4));  if (TILE_COL(P, 4)  < 64) pf_vmask |= 1u << 4;  \
        GLOAD(pf5,  TILE_ADDR(P, 5));  if (TILE_COL(P, 5)  < 64) pf_vmask |= 1u << 5;  \
        GLOAD(pf6,  TILE_ADDR(P, 6));  if (TILE_COL(P, 6)  < 64) pf_vmask |= 1u << 6;  \
        GLOAD(pf7,  TILE_ADDR(P, 7));  if (TILE_COL(P, 7)  < 64) pf_vmask |= 1u << 7;  \
        GLOAD(pf8,  TILE_ADDR(P, 8));  if (TILE_COL(P, 8)  < 64) pf_vmask |= 1u << 8;  \
        GLOAD(pf9,  TILE_ADDR(P, 9));  if (TILE_COL(P, 9)  < 64) pf_vmask |= 1u << 9;  \
        GLOAD(pf10, TILE_ADDR(P, 10)); if (TILE_COL(P, 10) < 64) pf_vmask |= 1u << 10; \
    } while (0)

#define NEXTROW2(rk)                                                           \
    int rk;                                                                    \
    {                                                                          \
        if (xA) { int bb_ = __builtin_ctzll(xA); xA &= xA - 1; rk = baseA + bb_; } \
        else if (xB) { int bb_ = __builtin_ctzll(xB); xB &= xB - 1; rk = baseB + bb_; } \
        else rk = rpad;                                                        \
    }

__global__ __launch_bounds__(512, 1) void nms_scan_kernel(
    const unsigned long long* __restrict__ colmaj,
    const unsigned long long* __restrict__ rowmaj,
    const float4* __restrict__ sortedBoxes,
    float* __restrict__ out) {
    int b = blockIdx.x;
    int tid = threadIdx.x;
    int lane = tid & 63;
    int wv = tid >> 6;   // 0 decider, 1 prefetch, 2 helper, 3..7 loaders
    const unsigned long long* C = colmaj + (size_t)b * MASK_WORDS * SORT_N;
    const unsigned long long* R = rowmaj + (size_t)b * SORT_N * MASK_WORDS;

    __shared__ int kept[POST_NMS];
    __shared__ unsigned remW[MASK_WORDS][2];            // [word][lo,hi]
    __shared__ unsigned long long aliveLds[MASK_WORDS];
    __shared__ unsigned long long ring[4][11][64];      // tile ring, slot = pair&3
    __shared__ unsigned long long car2[2][2];           // helper d2 carries, slot = pair&1
    __shared__ int doneLds;
    __shared__ int kcntLds;

    if (tid < MASK_WORDS) { remW[tid][0] = 0u; remW[tid][1] = 0u; aliveLds[tid] = 0ull; }
    if (tid < 4) car2[tid >> 1][tid & 1] = 0ull;
    if (tid == 0) { doneLds = 0; kcntLds = 0; }

    // pipeline registers (per-wave roles; wave-uniform control flow)
    unsigned long long pf0=0,pf1=0,pf2=0,pf3=0,pf4=0,pf5=0,pf6=0,pf7=0,pf8=0,pf9=0,pf10=0;
    unsigned pf_vmask = 0u;
    bool pf_have = false;
    unsigned long long gp0=0,gp1=0,gp2=0,gp3=0,gp4=0,gp5=0,gp6=0,gp7=0;
    bool ld_valid = false;

    // ---- prologue: stage pair 0 synchronously, issue pair 1 (in flight) ----
    if (wv == 1) {
        for (int t = 0; t < 11; ++t) {
            int col = TILE_COL(0, t);
            unsigned long long v =
                (col < 64) ? C[(size_t)col * SORT_N + TILE_RB(0, t) + lane] : 0ull;
            ring[0][t][lane] = v;
        }
        ISSUE_PAIR(1);
        pf_have = true;
    }
    block_sync();

    unsigned long long carA = 0ull, carB = 0ull;   // decider: d1 carries (pair q-1 -> q)
    int kcnt = 0;

    for (int q = 0; q < NPAIR; ++q) {
        if (wv == 0) {
            // ---------------- decider: pair q ----------------
            int A = 2 * q, Bg = A + 1, slot = q & 3;
            unsigned long long dA  = ring[slot][0][lane];
            unsigned long long tA1 = ring[slot][1][lane];
            unsigned long long tA2 = ring[slot][2][lane];
            unsigned long long tA3 = ring[slot][3][lane];
            unsigned long long dB  = ring[slot][6][lane];
            unsigned long long tB1 = ring[slot][7][lane];
            unsigned long long tB2 = ring[slot][8][lane];
            unsigned long long remA =
                ((unsigned long long)remW[A][1] << 32) | (unsigned long long)remW[A][0];
            unsigned long long remB =
                ((unsigned long long)remW[Bg][1] << 32) | (unsigned long long)remW[Bg][0];
            unsigned long long h2A = car2[q & 1][0];
            unsigned long long h2B = car2[q & 1][1];
            bool hit = false;
            unsigned long long aliveA = 0ull, aliveB = 0ull;
            unsigned long long pend = ~(remA | carA | h2A);
            while (pend) {
                int bit = __builtin_ctzll(pend);
                if (lane == 0) kept[kcnt] = (A << 6) + bit;
                ++kcnt;
                aliveA |= 1ull << bit;
                if (kcnt == POST_NMS) { hit = true; break; }
                pend &= ~(rl64(dA, bit) | (1ull << bit));
            }
            if (!hit) {
                unsigned long long nA1 = redor64(aliveA, tA1, lane);
                pend = ~(remB | carB | h2B | nA1);
                while (pend) {
                    int bit = __builtin_ctzll(pend);
                    if (lane == 0) kept[kcnt] = (Bg << 6) + bit;
                    ++kcnt;
                    aliveB |= 1ull << bit;
                    if (kcnt == POST_NMS) { hit = true; break; }
                    pend &= ~(rl64(dB, bit) | (1ull << bit));
                }
            }
            carA = redor64(aliveA, tA2, lane) | redor64(aliveB, tB1, lane);
            carB = redor64(aliveA, tA3, lane) | redor64(aliveB, tB2, lane);
            if (lane == 0) {
                aliveLds[A]  = aliveA;
                aliveLds[Bg] = aliveB;
                kcntLds = kcnt;
                if (hit) doneLds = 1;
            }
        } else if (wv == 1) {
            // ---------------- prefetch: write pair q+1, issue pair q+2 ------
            if (pf_have) {
                WAITV0;
                SCHED0;
                int wp = q + 1;
                if (wp < NPAIR) {
                    int ws = wp & 3;
                    ring[ws][0][lane]  = (pf_vmask & (1u << 0))  ? pf0  : 0ull;
                    ring[ws][1][lane]  = (pf_vmask & (1u << 1))  ? pf1  : 0ull;
                    ring[ws][2][lane]  = (pf_vmask & (1u << 2))  ? pf2  : 0ull;
                    ring[ws][3][lane]  = (pf_vmask & (1u << 3))  ? pf3  : 0ull;
                    ring[ws][4][lane]  = (pf_vmask & (1u << 4))  ? pf4  : 0ull;
                    ring[ws][5][lane]  = (pf_vmask & (1u << 5))  ? pf5  : 0ull;
                    ring[ws][6][lane]  = (pf_vmask & (1u << 6))  ? pf6  : 0ull;
                    ring[ws][7][lane]  = (pf_vmask & (1u << 7))  ? pf7  : 0ull;
                    ring[ws][8][lane]  = (pf_vmask & (1u << 8))  ? pf8  : 0ull;
                    ring[ws][9][lane]  = (pf_vmask & (1u << 9))  ? pf9  : 0ull;
                    ring[ws][10][lane] = (pf_vmask & (1u << 10)) ? pf10 : 0ull;
                }
                pf_have = false;
            }
            int ip = q + 2;
            if (ip < NPAIR) {
                ISSUE_PAIR(ip);
                pf_have = true;
            }
        } else if (wv == 2) {
            // ---------------- helper: pair p=q-1 d2 carries -> pair q+1 -----
            if (q >= 1) {
                int p = q - 1, sp = p & 3;
                unsigned long long aA = aliveLds[2 * p];
                unsigned long long aB = aliveLds[2 * p + 1];
                unsigned long long tA4 = ring[sp][4][lane];
                unsigned long long tA5 = ring[sp][5][lane];
                unsigned long long tB3 = ring[sp][9][lane];
                unsigned long long tB4 = ring[sp][10][lane];
                unsigned long long c0 = redor64(aA, tA4, lane) | redor64(aB, tB3, lane);
                unsigned long long c1 = redor64(aA, tA5, lane) | redor64(aB, tB4, lane);
                if (lane == 0) {
                    car2[(q + 1) & 1][0] = c0;
                    car2[(q + 1) & 1][1] = c1;
                }
            }
        } else {
            // ---------------- loaders: fold prev batch, issue pair q-1 ------
            if (ld_valid) {
                WAITV0;
                SCHED0;
                unsigned long long acc =
                    ((gp0 | gp1) | (gp2 | gp3)) | ((gp4 | gp5) | (gp6 | gp7));
                unsigned lo = (unsigned)acc, hi = (unsigned)(acc >> 32);
                if (lo) atomicOr(&remW[lane][0], lo);
                if (hi) atomicOr(&remW[lane][1], hi);
                ld_valid = false;
            }
            if (q >= 1) {
                int p = q - 1, gA = 2 * p, gB = 2 * p + 1;
                unsigned long long aA = aliveLds[gA];
                unsigned long long aB = aliveLds[gB];
                int k = wv - 3;                       // 0..NLW-1
                unsigned long long below = (1ull << lane) - 1ull;
                bool inA = (aA >> lane) & 1ull;
                bool inB = (aB >> lane) & 1ull;
                int posA = (int)__popcll(aA & below);
                int posB = (int)__popcll(aA) + (int)__popcll(aB & below);
                unsigned long long mA = __ballot(inA && (posA % NLW) == k);
                unsigned long long mB = __ballot(inB && (posB % NLW) == k);
                if (mA | mB) {
                    int baseA = gA << 6, baseB = gB << 6;
                    unsigned long long xA = mA, xB = mB;
                    int rpad = mA ? (baseA + __builtin_ctzll(mA))
                                  : (baseB + __builtin_ctzll(mB));
                    NEXTROW2(r0) NEXTROW2(r1) NEXTROW2(r2) NEXTROW2(r3)
                    NEXTROW2(r4) NEXTROW2(r5) NEXTROW2(r6) NEXTROW2(r7)
                    const unsigned long long* Rb = R + lane;
                    GLOAD(gp0, Rb + (size_t)r0 * MASK_WORDS);
                    GLOAD(gp1, Rb + (size_t)r1 * MASK_WORDS);
                    GLOAD(gp2, Rb + (size_t)r2 * MASK_WORDS);
                    GLOAD(gp3, Rb + (size_t)r3 * MASK_WORDS);
                    GLOAD(gp4, Rb + (size_t)r4 * MASK_WORDS);
                    GLOAD(gp5, Rb + (size_t)r5 * MASK_WORDS);
                    GLOAD(gp6, Rb + (size_t)r6 * MASK_WORDS);
                    GLOAD(gp7, Rb + (size_t)r7 * MASK_WORDS);
                    ld_valid = true;
                    // overflow rows (>8 for this wave): serial, fold NOW
                    // (early partial fold is an idempotent subset of carries)
                    unsigned long long ovf = 0ull;
                    while (xA) {
                        int bb = __builtin_ctzll(xA); xA &= xA - 1;
                        ovf |= Rb[(size_t)(baseA + bb) * MASK_WORDS];
                    }
                    while (xB) {
                        int bb = __builtin_ctzll(xB); xB &= xB - 1;
                        ovf |= Rb[(size_t)(baseB + bb) * MASK_WORDS];
                    }
                    if (ovf) {
                        unsigned lo = (unsigned)ovf, hi = (unsigned)(ovf >> 32);
                        if (lo) atomicOr(&remW[lane][0], lo);
                        if (hi) atomicOr(&remW[lane][1], hi);
                    }
                }
            }
        }
        block_sync();
        if (doneLds) break;
    }

    WAITV0;             // drain any in-flight asm loads before ending
    __syncthreads();

    int kc = kcntLds;   // last write barrier-ordered before every exit path
    for (int r = tid; r < POST_NMS; r += 512) {
        float* o = out + ((size_t)b * POST_NMS + r) * 5;
        float4 bx = make_float4(0.f, 0.f, 0.f, 0.f);
        if (r < kc) bx = sortedBoxes[(size_t)b * SORT_N + kept[r]];
        o[0] = (float)b;
        o[1] = bx.x;
        o[2] = bx.y;
        o[3] = bx.z;
        o[4] = bx.w;
    }
}

// ---------------------------------------------------------------------------
extern "C" void kernel_launch(void* const* d_in, const int* in_sizes, int n_in,
                              void* d_out, int out_size, void* d_ws, size_t ws_size,
                              hipStream_t stream) {
    const float* scores  = (const float*)d_in[0];
    const float* deltas  = (const float*)d_in[1];
    const float* im_info = (const float*)d_in[2];
    const float* anchors = (const float*)d_in[3];
    float* out = (float*)d_out;

    char* ws = (char*)d_ws;
    size_t off = 0;
    float4* boxes = (float4*)(ws + off);
    off += (size_t)B_N * N_PROP * sizeof(float4);
    off = (off + 255) & ~(size_t)255;
    unsigned long long* keys = (unsigned long long*)(ws + off);
    off += (size_t)B_N * N_PROP * sizeof(unsigned long long);
    off = (off + 255) & ~(size_t)255;
    float4* sortedBoxes = (float4*)(ws + off);
    off += (size_t)B_N * SORT_N * sizeof(float4);
    off = (off + 255) & ~(size_t)255;
    unsigned long long* colmaj = (unsigned long long*)(ws + off);
    off += (size_t)B_N * MASK_WORDS * SORT_N * sizeof(unsigned long long);
    off = (off + 255) & ~(size_t)255;
    unsigned long long* rowmaj = (unsigned long long*)(ws + off);
    off += (size_t)B_N * SORT_N * MASK_WORDS * sizeof(unsigned long long);
    off = (off + 255) & ~(size_t)255;
    unsigned long long* cand = (unsigned long long*)(ws + off);
    off += (size_t)B_N * CAND_MAX * sizeof(unsigned long long);
    off = (off + 255) & ~(size_t)255;
    unsigned* ghist = (unsigned*)(ws + off);
    size_t zero_off = off;
    off += (size_t)B_N * NBINS * sizeof(unsigned);
    unsigned* cnt = (unsigned*)(ws + off);
    off += (size_t)B_N * sizeof(unsigned);
    size_t zero_bytes = off - zero_off;
    off = (off + 255) & ~(size_t)255;
    int* Tbuf = (int*)(ws + off);
    off += (size_t)B_N * sizeof(int);

    hipMemsetAsync((void*)ghist, 0, zero_bytes, stream);

    int total = B_N * N_PROP;
    decode_kernel<<<(total + 255) / 256, 256, 0, stream>>>(
        scores, deltas, im_info, anchors, boxes, keys, ghist);
    findT_kernel<<<B_N, 64, 0, stream>>>(ghist, Tbuf);
    compact_kernel<<<dim3((N_PROP + 255) / 256, B_N), 256, 0, stream>>>(
        keys, Tbuf, cnt, cand);
    rank_scatter_kernel<<<dim3(CAND_MAX / 64, B_N), 256, 0, stream>>>(
        cand, cnt, boxes, sortedBoxes);
    iou_mask_kernel<<<dim3(520, B_N), 256, 0, stream>>>(sortedBoxes, colmaj, rowmaj);
    nms_scan_kernel<<<B_N, 512, 0, stream>>>(colmaj, rowmaj, sortedBoxes, out);
}

// Round 8
// 214.481 us; speedup vs baseline: 1.5003x; 1.2218x over previous
//
#include <hip/hip_runtime.h>
#include <stdint.h>

#define A_N 9
#define H_N 50
#define W_N 76
#define HW_N (H_N * W_N)      // 3800
#define N_PROP (A_N * HW_N)   // 34200
#define B_N 4
#define PRE_NMS 4000
#define POST_NMS 300
#define NMS_TH 0.7f
#define SORT_N 4096
#define MASK_WORDS 64
#define CAND_MAX 5120
#define NBINS 4096
#define NPAIR 32
#define NLW 5                 // loader waves
#define DEC_BLKS ((N_PROP + 255) / 256)   // 134, batch-aligned

// ---------------------------------------------------------------------------
// Kernel A: decode + keys. Histogram via per-block LDS privatization
// (Guideline 12): scores are N(0,1) -> ~50 hot exponent bins; direct global
// atomicAdd serialized ~2000-deep at L2 (r7: 55.5us at 1.6% HBM BW). Now:
// LDS hist (per-CU serialization, cheap) + flush nonzero bins only
// (per-hot-address chain 2000 -> ~134, pipelined at L2 op rate).
// ---------------------------------------------------------------------------
__global__ __launch_bounds__(256) void decode_kernel(
    const float* __restrict__ scores,
    const float* __restrict__ deltas,
    const float* __restrict__ im_info,
    const float* __restrict__ anchors,
    float4* __restrict__ boxes,
    unsigned long long* __restrict__ keys,
    unsigned* __restrict__ ghist) {
#pragma clang fp contract(off)
    __shared__ unsigned hist[NBINS];
    int tid = threadIdx.x;
    int b = blockIdx.y;
    int r = blockIdx.x * 256 + tid;
#pragma unroll
    for (int i = 0; i < NBINS / 256; ++i) hist[tid + i * 256] = 0u;
    __syncthreads();

    if (r < N_PROP) {
        int a = r / HW_N;          // fixed across a wave
        int hw = r - a * HW_N;     // consecutive across lanes
        int hy = hw / W_N;
        int wx = hw - hy * W_N;

        float sx = (float)wx * 16.0f;
        float sy = (float)hy * 16.0f;
        float ax1 = anchors[a * 4 + 0] + sx;
        float ay1 = anchors[a * 4 + 1] + sy;
        float ax2 = anchors[a * 4 + 2] + sx;
        float ay2 = anchors[a * 4 + 3] + sy;
        float aw = ax2 - ax1 + 1.0f;
        float ah = ay2 - ay1 + 1.0f;
        float cx = ax1 + 0.5f * aw;
        float cy = ay1 + 0.5f * ah;

        const float* db = deltas + ((size_t)b * 36 + (size_t)a * 4) * HW_N + hw;
        float d0 = db[0];
        float d1 = db[HW_N];
        float d2 = db[2 * HW_N];
        float d3 = db[3 * HW_N];

        float pcx = d0 * aw + cx;
        float pcy = d1 * ah + cy;
        float pw  = expf(d2) * aw;
        float ph  = expf(d3) * ah;

        float x1 = pcx - 0.5f * pw;
        float y1 = pcy - 0.5f * ph;
        float x2 = pcx + 0.5f * pw;
        float y2 = pcy + 0.5f * ph;

        float xhi = im_info[b * 3 + 1] - 1.0f;
        float yhi = im_info[b * 3 + 0] - 1.0f;
        x1 = fminf(fmaxf(x1, 0.0f), xhi);
        y1 = fminf(fmaxf(y1, 0.0f), yhi);
        x2 = fminf(fmaxf(x2, 0.0f), xhi);
        y2 = fminf(fmaxf(y2, 0.0f), yhi);

        boxes[(size_t)b * N_PROP + r] = make_float4(x1, y1, x2, y2);  // a-major

        float s = scores[((size_t)b * A_N + a) * HW_N + hw];
        unsigned f = __float_as_uint(s);
        unsigned sk = f ^ ((f & 0x80000000u) ? 0xFFFFFFFFu : 0x80000000u);
        unsigned n_ref = (unsigned)(hw * A_N + a);
        unsigned long long key = ((unsigned long long)sk << 32) | (unsigned)(~n_ref);
        keys[(size_t)b * N_PROP + r] = key;
        atomicAdd(&hist[(unsigned)(key >> 52)], 1u);
    }
    __syncthreads();
#pragma unroll
    for (int i = 0; i < NBINS / 256; ++i) {
        unsigned v = hist[tid + i * 256];
        if (v) atomicAdd(&ghist[b * NBINS + tid + i * 256], v);
    }
}

// ---------------------------------------------------------------------------
// Kernel B: threshold bucket T via two wave-level suffix scans.
// ---------------------------------------------------------------------------
__global__ __launch_bounds__(64) void findT_kernel(const unsigned* __restrict__ ghist,
                                                   int* __restrict__ Tout) {
    __shared__ unsigned h[NBINS];
    int b = blockIdx.x;
    int lane = threadIdx.x;  // 64
    for (int i = lane; i < NBINS; i += 64) h[i] = ghist[b * NBINS + i];
    __syncthreads();
    unsigned gsum = 0;
    for (int j = 0; j < 64; ++j) gsum += h[lane * 64 + j];
    unsigned s = gsum;
    for (int d = 1; d < 64; d <<= 1) {
        unsigned t = (unsigned)__shfl_down((int)s, d);
        if (lane + d < 64) s += t;
    }
    unsigned long long bal = __ballot(s >= PRE_NMS);
    int gstar = 63 - __builtin_clzll(bal);
    unsigned after = (gstar < 63) ? (unsigned)__builtin_amdgcn_readlane((int)s, gstar + 1) : 0u;
    unsigned R = PRE_NMS - after;
    unsigned s2 = h[gstar * 64 + lane];
    for (int d = 1; d < 64; d <<= 1) {
        unsigned t = (unsigned)__shfl_down((int)s2, d);
        if (lane + d < 64) s2 += t;
    }
    unsigned long long bal2 = __ballot(s2 >= R);
    int j = 63 - __builtin_clzll(bal2);
    if (lane == 0) Tout[b] = gstar * 64 + j;
}

// ---------------------------------------------------------------------------
// Kernel C: compact candidates; wave-aggregated atomic.
// ---------------------------------------------------------------------------
__global__ void compact_kernel(const unsigned long long* __restrict__ keys,
                               const int* __restrict__ T,
                               unsigned* __restrict__ cnt,
                               unsigned long long* __restrict__ cand) {
    int b = blockIdx.y;
    int n = blockIdx.x * 256 + threadIdx.x;
    bool pred = false;
    unsigned long long k = 0ull;
    if (n < N_PROP) {
        k = keys[(size_t)b * N_PROP + n];
        pred = ((int)(unsigned)(k >> 52) >= T[b]);
    }
    unsigned long long m = __ballot(pred);
    if (m) {
        int lane = threadIdx.x & 63;
        int lead = __ffsll((unsigned long long)m) - 1;
        unsigned base = 0;
        if (lane == lead) base = atomicAdd(&cnt[b], (unsigned)__popcll(m));
        base = __shfl((int)base, lead);
        if (pred) {
            unsigned pos = base + (unsigned)__popcll(m & ((1ull << lane) - 1ull));
            if (pos < CAND_MAX) cand[(size_t)b * CAND_MAX + pos] = k;
        }
    }
}

// ---------------------------------------------------------------------------
// Kernel D: exact rank by pairwise count, 4-way j-split per candidate.
// ---------------------------------------------------------------------------
__global__ __launch_bounds__(256) void rank_scatter_kernel(
    const unsigned long long* __restrict__ cand,
    const unsigned* __restrict__ cnt,
    const float4* __restrict__ boxes,
    float4* __restrict__ sortedBoxes) {
    __shared__ unsigned long long sk[256];
    int b = blockIdx.y;
    int tid = threadIdx.x;
    int ci = blockIdx.x * 64 + (tid >> 2);
    int q = tid & 3;
    int mc = (int)min(cnt[b], (unsigned)CAND_MAX);
    unsigned long long my = (ci < mc) ? cand[(size_t)b * CAND_MAX + ci] : 0ull;
    int rank = 0;
    int nt = (mc + 255) >> 8;
    for (int t = 0; t < nt; ++t) {
        int j = t * 256 + tid;
        sk[tid] = (j < mc) ? cand[(size_t)b * CAND_MAX + j] : 0ull;
        __syncthreads();
#pragma unroll 16
        for (int c = 0; c < 64; ++c) {
            int cc = q * 64 + ((c + q * 17) & 63);  // stagger: avoid 4-way bank conflict
            rank += (sk[cc] > my) ? 1 : 0;
        }
        __syncthreads();
    }
    rank += __shfl_xor(rank, 1);
    rank += __shfl_xor(rank, 2);
    if (q == 0 && ci < mc && rank < PRE_NMS) {
        unsigned n_ref = ~(unsigned)(my & 0xFFFFFFFFull);
        unsigned a = n_ref % A_N;
        unsigned hw = n_ref / A_N;
        sortedBoxes[(size_t)b * SORT_N + rank] =
            boxes[(size_t)b * N_PROP + a * HW_N + hw];
    }
    if (q == 1) {
        int pi = blockIdx.x * 64 + (tid >> 2);
        if (pi >= PRE_NMS && pi < SORT_N)
            sortedBoxes[(size_t)b * SORT_N + pi] = make_float4(0.f, 0.f, 0.f, 0.f);
    }
}

// ---------------------------------------------------------------------------
// Kernel E: suppression bitmask, upper-triangle-only grid (2080 tiles/batch,
// 4 waves/block).
//   colmaj[cc*SORT_N + r]  (coalesced store; prefetch wave's tile reads)
//   rowmaj[r*64 + cc]      (scatter store; loader waves' row reads COALESCED)
// ---------------------------------------------------------------------------
__global__ __launch_bounds__(256) void iou_mask_kernel(
    const float4* __restrict__ sortedBoxes,
    unsigned long long* __restrict__ colmaj,
    unsigned long long* __restrict__ rowmaj) {
#pragma clang fp contract(off)
    int b = blockIdx.y;
    int wv = threadIdx.x >> 6;
    int t = threadIdx.x & 63;
    int k = blockIdx.x * 4 + wv;          // 0..2079, upper-tri linear index
    int rc = 0;
    while (k >= 64 - rc) { k -= 64 - rc; ++rc; }
    int cc = rc + k;

    __shared__ float4 colb[4][64];
    colb[wv][t] = sortedBoxes[(size_t)b * SORT_N + cc * 64 + t];
    __syncthreads();

    int r = rc * 64 + t;
    float4 rb = sortedBoxes[(size_t)b * SORT_N + r];
    float rarea = (rb.z - rb.x) * (rb.w - rb.y);
    unsigned long long word = 0ull;
    for (int c = 0; c < 64; ++c) {
        int j = cc * 64 + c;
        float4 cb = colb[wv][c];
        float carea = (cb.z - cb.x) * (cb.w - cb.y);
        float ltx = fmaxf(rb.x, cb.x);
        float lty = fmaxf(rb.y, cb.y);
        float rbx = fminf(rb.z, cb.z);
        float rby = fminf(rb.w, cb.w);
        float iw = fmaxf(rbx - ltx, 0.0f);
        float ih = fmaxf(rby - lty, 0.0f);
        float inter = iw * ih;
        float iou = inter / (rarea + carea - inter + 1e-9f);
        if (iou > NMS_TH && j > r) word |= (1ull << c);
    }
    colmaj[((size_t)b * MASK_WORDS + cc) * SORT_N + r] = word;   // coalesced
    rowmaj[((size_t)b * SORT_N + r) * MASK_WORDS + cc] = word;   // scatter
}

// ---------------------------------------------------------------------------
// Kernel F: MULTI-WAVE greedy scan, RAW-BARRIER PIPELINED (r7 structure,
// unchanged; 53us, compute/sync-bound per r7 counters: L2-warm dispatch with
// FETCH=24KB still took 53.4us).
// ---------------------------------------------------------------------------
__device__ __forceinline__ unsigned long long rl64(unsigned long long v, int src) {
    unsigned lo = (unsigned)__builtin_amdgcn_readlane((int)(unsigned)(v & 0xFFFFFFFFull), src);
    unsigned hi = (unsigned)__builtin_amdgcn_readlane((int)(unsigned)(v >> 32), src);
    return ((unsigned long long)hi << 32) | lo;
}

__device__ __forceinline__ unsigned long long redor64(unsigned long long alive,
                                                      unsigned long long v, int lane) {
    unsigned long long x = ((alive >> lane) & 1ull) ? v : 0ull;
    x |= __shfl_xor(x, 1);
    x |= __shfl_xor(x, 2);
    x |= __shfl_xor(x, 4);
    x |= __shfl_xor(x, 8);
    x |= __shfl_xor(x, 16);
    x |= __shfl_xor(x, 32);
    return x;
}

__device__ __forceinline__ void block_sync() {
    asm volatile("s_waitcnt lgkmcnt(0)" ::: "memory");   // LDS visibility, NO vmcnt drain
    __builtin_amdgcn_s_barrier();
    asm volatile("" ::: "memory");                       // compiler fence after barrier
}

#define GLOAD(dst, addr) \
    asm volatile("global_load_dwordx2 %0, %1, off" : "=v"(dst) : "v"(addr))
#define WAITV0 asm volatile("s_waitcnt vmcnt(0)" ::: "memory")
#define SCHED0 __builtin_amdgcn_sched_barrier(0)

// tile t of pair P: t<6 -> col 2P+t over rows of group 2P; t>=6 -> col
// 2P+1+(t-6) over rows of group 2P+1. Clamp col for address, zero on write.
#define TILE_COL(P, t) ((t) < 6 ? 2 * (P) + (t) : 2 * (P) + 1 + ((t) - 6))
#define TILE_RB(P, t)  ((size_t)((t) < 6 ? 2 * (P) : 2 * (P) + 1) << 6)
#define TILE_ADDR(P, t) \
    (C + (size_t)(TILE_COL(P, t) < 64 ? TILE_COL(P, t) : 63) * SORT_N + TILE_RB(P, t) + lane)

#define ISSUE_PAIR(P)                                                          \
    do {                                                                       \
        pf_vmask = 0u;                                                         \
        GLOAD(pf0,  TILE_ADDR(P, 0));  if (TILE_COL(P, 0)  < 64) pf_vmask |= 1u << 0;  \
        GLOAD(pf1,  TILE_ADDR(P, 1));  if (TILE_COL(P, 1)  < 64) pf_vmask |= 1u << 1;  \
        GLOAD(pf2,  TILE_ADDR(P, 2));  if (TILE_COL(P, 2)  < 64) pf_vmask |= 1u << 2;  \
        GLOAD(pf3,  TILE_ADDR(P, 3));  if (TILE_COL(P, 3)  < 64) pf_vmask |= 1u << 3;  \
        GLOAD(pf4,  TILE_ADDR(P, 4));  if (TILE_COL(P, 4)  < 64) pf_vmask |= 1u << 4;  \
        GLOAD(pf5,  TILE_ADDR(P, 5));  if (TILE_COL(P, 5)  < 64) pf_vmask |= 1u << 5;  \
        GLOAD(pf6,  TILE_ADDR(P, 6));  if (TILE_COL(P, 6)  < 64) pf_vmask |= 1u << 6;  \
        GLOAD(pf7,  TILE_ADDR(P, 7));  if (TILE_COL(P, 7)  < 64) pf_vmask |= 1u << 7;  \
        GLOAD(pf8,  TILE_ADDR(P, 8));  if (TILE_COL(P, 8)  < 64) pf_vmask |= 1u << 8;  \
        GLOAD(pf9,  TILE_ADDR(P, 9));  if (TILE_COL(P, 9)  < 64) pf_vmask |= 1u << 9;  \
        GLOAD(pf10, TILE_ADDR(P, 10)); if (TILE_COL(P, 10) < 64) pf_vmask |= 1u << 10; \
    } while (0)

#define NEXTROW2(rk)                                                           \
    int rk;                                                                    \
    {                                                                          \
        if (xA) { int bb_ = __builtin_ctzll(xA); xA &= xA - 1; rk = baseA + bb_; } \
        else if (xB) { int bb_ = __builtin_ctzll(xB); xB &= xB - 1; rk = baseB + bb_; } \
        else rk = rpad;                                                        \
    }

__global__ __launch_bounds__(512, 1) void nms_scan_kernel(
    const unsigned long long* __restrict__ colmaj,
    const unsigned long long* __restrict__ rowmaj,
    const float4* __restrict__ sortedBoxes,
    float* __restrict__ out) {
    int b = blockIdx.x;
    int tid = threadIdx.x;
    int lane = tid & 63;
    int wv = tid >> 6;   // 0 decider, 1 prefetch, 2 helper, 3..7 loaders
    const unsigned long long* C = colmaj + (size_t)b * MASK_WORDS * SORT_N;
    const unsigned long long* R = rowmaj + (size_t)b * SORT_N * MASK_WORDS;

    __shared__ int kept[POST_NMS];
    __shared__ unsigned remW[MASK_WORDS][2];            // [word][lo,hi]
    __shared__ unsigned long long aliveLds[MASK_WORDS];
    __shared__ unsigned long long ring[4][11][64];      // tile ring, slot = pair&3
    __shared__ unsigned long long car2[2][2];           // helper d2 carries, slot = pair&1
    __shared__ int doneLds;
    __shared__ int kcntLds;

    if (tid < MASK_WORDS) { remW[tid][0] = 0u; remW[tid][1] = 0u; aliveLds[tid] = 0ull; }
    if (tid < 4) car2[tid >> 1][tid & 1] = 0ull;
    if (tid == 0) { doneLds = 0; kcntLds = 0; }

    // pipeline registers (per-wave roles; wave-uniform control flow)
    unsigned long long pf0=0,pf1=0,pf2=0,pf3=0,pf4=0,pf5=0,pf6=0,pf7=0,pf8=0,pf9=0,pf10=0;
    unsigned pf_vmask = 0u;
    bool pf_have = false;
    unsigned long long gp0=0,gp1=0,gp2=0,gp3=0,gp4=0,gp5=0,gp6=0,gp7=0;
    bool ld_valid = false;

    // ---- prologue: stage pair 0 synchronously, issue pair 1 (in flight) ----
    if (wv == 1) {
        for (int t = 0; t < 11; ++t) {
            int col = TILE_COL(0, t);
            unsigned long long v =
                (col < 64) ? C[(size_t)col * SORT_N + TILE_RB(0, t) + lane] : 0ull;
            ring[0][t][lane] = v;
        }
        ISSUE_PAIR(1);
        pf_have = true;
    }
    block_sync();

    unsigned long long carA = 0ull, carB = 0ull;   // decider: d1 carries (pair q-1 -> q)
    int kcnt = 0;

    for (int q = 0; q < NPAIR; ++q) {
        if (wv == 0) {
            // ---------------- decider: pair q ----------------
            int A = 2 * q, Bg = A + 1, slot = q & 3;
            unsigned long long dA  = ring[slot][0][lane];
            unsigned long long tA1 = ring[slot][1][lane];
            unsigned long long tA2 = ring[slot][2][lane];
            unsigned long long tA3 = ring[slot][3][lane];
            unsigned long long dB  = ring[slot][6][lane];
            unsigned long long tB1 = ring[slot][7][lane];
            unsigned long long tB2 = ring[slot][8][lane];
            unsigned long long remA =
                ((unsigned long long)remW[A][1] << 32) | (unsigned long long)remW[A][0];
            unsigned long long remB =
                ((unsigned long long)remW[Bg][1] << 32) | (unsigned long long)remW[Bg][0];
            unsigned long long h2A = car2[q & 1][0];
            unsigned long long h2B = car2[q & 1][1];
            bool hit = false;
            unsigned long long aliveA = 0ull, aliveB = 0ull;
            unsigned long long pend = ~(remA | carA | h2A);
            while (pend) {
                int bit = __builtin_ctzll(pend);
                if (lane == 0) kept[kcnt] = (A << 6) + bit;
                ++kcnt;
                aliveA |= 1ull << bit;
                if (kcnt == POST_NMS) { hit = true; break; }
                pend &= ~(rl64(dA, bit) | (1ull << bit));
            }
            if (!hit) {
                unsigned long long nA1 = redor64(aliveA, tA1, lane);
                pend = ~(remB | carB | h2B | nA1);
                while (pend) {
                    int bit = __builtin_ctzll(pend);
                    if (lane == 0) kept[kcnt] = (Bg << 6) + bit;
                    ++kcnt;
                    aliveB |= 1ull << bit;
                    if (kcnt == POST_NMS) { hit = true; break; }
                    pend &= ~(rl64(dB, bit) | (1ull << bit));
                }
            }
            carA = redor64(aliveA, tA2, lane) | redor64(aliveB, tB1, lane);
            carB = redor64(aliveA, tA3, lane) | redor64(aliveB, tB2, lane);
            if (lane == 0) {
                aliveLds[A]  = aliveA;
                aliveLds[Bg] = aliveB;
                kcntLds = kcnt;
                if (hit) doneLds = 1;
            }
        } else if (wv == 1) {
            // ---------------- prefetch: write pair q+1, issue pair q+2 ------
            if (pf_have) {
                WAITV0;
                SCHED0;
                int wp = q + 1;
                if (wp < NPAIR) {
                    int ws = wp & 3;
                    ring[ws][0][lane]  = (pf_vmask & (1u << 0))  ? pf0  : 0ull;
                    ring[ws][1][lane]  = (pf_vmask & (1u << 1))  ? pf1  : 0ull;
                    ring[ws][2][lane]  = (pf_vmask & (1u << 2))  ? pf2  : 0ull;
                    ring[ws][3][lane]  = (pf_vmask & (1u << 3))  ? pf3  : 0ull;
                    ring[ws][4][lane]  = (pf_vmask & (1u << 4))  ? pf4  : 0ull;
                    ring[ws][5][lane]  = (pf_vmask & (1u << 5))  ? pf5  : 0ull;
                    ring[ws][6][lane]  = (pf_vmask & (1u << 6))  ? pf6  : 0ull;
                    ring[ws][7][lane]  = (pf_vmask & (1u << 7))  ? pf7  : 0ull;
                    ring[ws][8][lane]  = (pf_vmask & (1u << 8))  ? pf8  : 0ull;
                    ring[ws][9][lane]  = (pf_vmask & (1u << 9))  ? pf9  : 0ull;
                    ring[ws][10][lane] = (pf_vmask & (1u << 10)) ? pf10 : 0ull;
                }
                pf_have = false;
            }
            int ip = q + 2;
            if (ip < NPAIR) {
                ISSUE_PAIR(ip);
                pf_have = true;
            }
        } else if (wv == 2) {
            // ---------------- helper: pair p=q-1 d2 carries -> pair q+1 -----
            if (q >= 1) {
                int p = q - 1, sp = p & 3;
                unsigned long long aA = aliveLds[2 * p];
                unsigned long long aB = aliveLds[2 * p + 1];
                unsigned long long tA4 = ring[sp][4][lane];
                unsigned long long tA5 = ring[sp][5][lane];
                unsigned long long tB3 = ring[sp][9][lane];
                unsigned long long tB4 = ring[sp][10][lane];
                unsigned long long c0 = redor64(aA, tA4, lane) | redor64(aB, tB3, lane);
                unsigned long long c1 = redor64(aA, tA5, lane) | redor64(aB, tB4, lane);
                if (lane == 0) {
                    car2[(q + 1) & 1][0] = c0;
                    car2[(q + 1) & 1][1] = c1;
                }
            }
        } else {
            // ---------------- loaders: fold prev batch, issue pair q-1 ------
            if (ld_valid) {
                WAITV0;
                SCHED0;
                unsigned long long acc =
                    ((gp0 | gp1) | (gp2 | gp3)) | ((gp4 | gp5) | (gp6 | gp7));
                unsigned lo = (unsigned)acc, hi = (unsigned)(acc >> 32);
                if (lo) atomicOr(&remW[lane][0], lo);
                if (hi) atomicOr(&remW[lane][1], hi);
                ld_valid = false;
            }
            if (q >= 1) {
                int p = q - 1, gA = 2 * p, gB = 2 * p + 1;
                unsigned long long aA = aliveLds[gA];
                unsigned long long aB = aliveLds[gB];
                int k = wv - 3;                       // 0..NLW-1
                unsigned long long below = (1ull << lane) - 1ull;
                bool inA = (aA >> lane) & 1ull;
                bool inB = (aB >> lane) & 1ull;
                int posA = (int)__popcll(aA & below);
                int posB = (int)__popcll(aA) + (int)__popcll(aB & below);
                unsigned long long mA = __ballot(inA && (posA % NLW) == k);
                unsigned long long mB = __ballot(inB && (posB % NLW) == k);
                if (mA | mB) {
                    int baseA = gA << 6, baseB = gB << 6;
                    unsigned long long xA = mA, xB = mB;
                    int rpad = mA ? (baseA + __builtin_ctzll(mA))
                                  : (baseB + __builtin_ctzll(mB));
                    NEXTROW2(r0) NEXTROW2(r1) NEXTROW2(r2) NEXTROW2(r3)
                    NEXTROW2(r4) NEXTROW2(r5) NEXTROW2(r6) NEXTROW2(r7)
                    const unsigned long long* Rb = R + lane;
                    GLOAD(gp0, Rb + (size_t)r0 * MASK_WORDS);
                    GLOAD(gp1, Rb + (size_t)r1 * MASK_WORDS);
                    GLOAD(gp2, Rb + (size_t)r2 * MASK_WORDS);
                    GLOAD(gp3, Rb + (size_t)r3 * MASK_WORDS);
                    GLOAD(gp4, Rb + (size_t)r4 * MASK_WORDS);
                    GLOAD(gp5, Rb + (size_t)r5 * MASK_WORDS);
                    GLOAD(gp6, Rb + (size_t)r6 * MASK_WORDS);
                    GLOAD(gp7, Rb + (size_t)r7 * MASK_WORDS);
                    ld_valid = true;
                    // overflow rows (>8 for this wave): serial, fold NOW
                    // (early partial fold is an idempotent subset of carries)
                    unsigned long long ovf = 0ull;
                    while (xA) {
                        int bb = __builtin_ctzll(xA); xA &= xA - 1;
                        ovf |= Rb[(size_t)(baseA + bb) * MASK_WORDS];
                    }
                    while (xB) {
                        int bb = __builtin_ctzll(xB); xB &= xB - 1;
                        ovf |= Rb[(size_t)(baseB + bb) * MASK_WORDS];
                    }
                    if (ovf) {
                        unsigned lo = (unsigned)ovf, hi = (unsigned)(ovf >> 32);
                        if (lo) atomicOr(&remW[lane][0], lo);
                        if (hi) atomicOr(&remW[lane][1], hi);
                    }
                }
            }
        }
        block_sync();
        if (doneLds) break;
    }

    WAITV0;             // drain any in-flight asm loads before ending
    __syncthreads();

    int kc = kcntLds;   // last write barrier-ordered before every exit path
    for (int r = tid; r < POST_NMS; r += 512) {
        float* o = out + ((size_t)b * POST_NMS + r) * 5;
        float4 bx = make_float4(0.f, 0.f, 0.f, 0.f);
        if (r < kc) bx = sortedBoxes[(size_t)b * SORT_N + kept[r]];
        o[0] = (float)b;
        o[1] = bx.x;
        o[2] = bx.y;
        o[3] = bx.z;
        o[4] = bx.w;
    }
}

// ---------------------------------------------------------------------------
extern "C" void kernel_launch(void* const* d_in, const int* in_sizes, int n_in,
                              void* d_out, int out_size, void* d_ws, size_t ws_size,
                              hipStream_t stream) {
    const float* scores  = (const float*)d_in[0];
    const float* deltas  = (const float*)d_in[1];
    const float* im_info = (const float*)d_in[2];
    const float* anchors = (const float*)d_in[3];
    float* out = (float*)d_out;

    char* ws = (char*)d_ws;
    size_t off = 0;
    float4* boxes = (float4*)(ws + off);
    off += (size_t)B_N * N_PROP * sizeof(float4);
    off = (off + 255) & ~(size_t)255;
    unsigned long long* keys = (unsigned long long*)(ws + off);
    off += (size_t)B_N * N_PROP * sizeof(unsigned long long);
    off = (off + 255) & ~(size_t)255;
    float4* sortedBoxes = (float4*)(ws + off);
    off += (size_t)B_N * SORT_N * sizeof(float4);
    off = (off + 255) & ~(size_t)255;
    unsigned long long* colmaj = (unsigned long long*)(ws + off);
    off += (size_t)B_N * MASK_WORDS * SORT_N * sizeof(unsigned long long);
    off = (off + 255) & ~(size_t)255;
    unsigned long long* rowmaj = (unsigned long long*)(ws + off);
    off += (size_t)B_N * SORT_N * MASK_WORDS * sizeof(unsigned long long);
    off = (off + 255) & ~(size_t)255;
    unsigned long long* cand = (unsigned long long*)(ws + off);
    off += (size_t)B_N * CAND_MAX * sizeof(unsigned long long);
    off = (off + 255) & ~(size_t)255;
    unsigned* ghist = (unsigned*)(ws + off);
    size_t zero_off = off;
    off += (size_t)B_N * NBINS * sizeof(unsigned);
    unsigned* cnt = (unsigned*)(ws + off);
    off += (size_t)B_N * sizeof(unsigned);
    size_t zero_bytes = off - zero_off;
    off = (off + 255) & ~(size_t)255;
    int* Tbuf = (int*)(ws + off);
    off += (size_t)B_N * sizeof(int);

    hipMemsetAsync((void*)ghist, 0, zero_bytes, stream);

    decode_kernel<<<dim3(DEC_BLKS, B_N), 256, 0, stream>>>(
        scores, deltas, im_info, anchors, boxes, keys, ghist);
    findT_kernel<<<B_N, 64, 0, stream>>>(ghist, Tbuf);
    compact_kernel<<<dim3((N_PROP + 255) / 256, B_N), 256, 0, stream>>>(
        keys, Tbuf, cnt, cand);
    rank_scatter_kernel<<<dim3(CAND_MAX / 64, B_N), 256, 0, stream>>>(
        cand, cnt, boxes, sortedBoxes);
    iou_mask_kernel<<<dim3(520, B_N), 256, 0, stream>>>(sortedBoxes, colmaj, rowmaj);
    nms_scan_kernel<<<B_N, 512, 0, stream>>>(colmaj, rowmaj, sortedBoxes, out);
}